// Round 1
// baseline (1818.167 us; speedup 1.0000x reference)
//
#include <hip/hip_runtime.h>
#include <math.h>

#define NEG_SLOPE 0.2f

__device__ __forceinline__ float leaky(float x) { return x >= 0.f ? x : NEG_SLOPE * x; }

__device__ __forceinline__ void atomicMaxF(float* addr, float val) {
    int* ia = (int*)addr;
    int old = *ia;
    while (__int_as_float(old) < val) {
        int assumed = old;
        old = atomicCAS(ia, assumed, __float_as_int(val));
        if (old == assumed) break;
    }
}

__global__ void k_fill(float* p, long long n, float v) {
    long long i = blockIdx.x * (long long)blockDim.x + threadIdx.x;
    if (i < n) p[i] = v;
}

// h1 = x @ W1  [N,27]@[27,64], plus per-head scores s_src/s_dst [N,4]
__global__ void k_h1(const float* __restrict__ x, const float* __restrict__ W1,
                     const float* __restrict__ a_src, const float* __restrict__ a_dst,
                     float* __restrict__ h1, float* __restrict__ ssrc, float* __restrict__ sdst,
                     int N) {
    __shared__ float sW[27 * 64];
    for (int i = threadIdx.x; i < 27 * 64; i += blockDim.x) sW[i] = W1[i];
    __syncthreads();
    int wave = threadIdx.x >> 6;
    int lane = threadIdx.x & 63;
    int n = blockIdx.x * 4 + wave;
    if (n >= N) return;
    const float* xr = x + (size_t)n * 27;
    float acc = 0.f;
#pragma unroll
    for (int k = 0; k < 27; ++k) acc += xr[k] * sW[k * 64 + lane];
    h1[(size_t)n * 64 + lane] = acc;
    int hd = lane >> 4, c = lane & 15;
    float vs = acc * a_src[hd * 16 + c];
    float vd = acc * a_dst[hd * 16 + c];
#pragma unroll
    for (int off = 8; off >= 1; off >>= 1) {
        vs += __shfl_xor(vs, off);
        vd += __shfl_xor(vd, off);
    }
    if (c == 0) {
        ssrc[n * 4 + hd] = vs;
        sdst[n * 4 + hd] = vd;
    }
}

// segment max over dst, 4 heads, thread per edge (self loops appended: e>=E -> n=e-E)
__global__ void k_max1(const int* __restrict__ src, const int* __restrict__ dst, int E, int N,
                       const float* __restrict__ ssrc, const float* __restrict__ sdst,
                       float* __restrict__ m1) {
    int e = blockIdx.x * blockDim.x + threadIdx.x;
    if (e >= E + N) return;
    int s, d;
    if (e < E) { s = src[e]; d = dst[e]; } else { s = d = e - E; }
    float4 a = *(const float4*)(ssrc + (size_t)s * 4);
    float4 b = *(const float4*)(sdst + (size_t)d * 4);
    atomicMaxF(&m1[d * 4 + 0], leaky(a.x + b.x));
    atomicMaxF(&m1[d * 4 + 1], leaky(a.y + b.y));
    atomicMaxF(&m1[d * 4 + 2], leaky(a.z + b.z));
    atomicMaxF(&m1[d * 4 + 3], leaky(a.w + b.w));
}

__global__ void k_den1(const int* __restrict__ src, const int* __restrict__ dst, int E, int N,
                       const float* __restrict__ ssrc, const float* __restrict__ sdst,
                       const float* __restrict__ m1, float* __restrict__ den1) {
    int e = blockIdx.x * blockDim.x + threadIdx.x;
    if (e >= E + N) return;
    int s, d;
    if (e < E) { s = src[e]; d = dst[e]; } else { s = d = e - E; }
    float4 a = *(const float4*)(ssrc + (size_t)s * 4);
    float4 b = *(const float4*)(sdst + (size_t)d * 4);
    float4 m = *(const float4*)(m1 + (size_t)d * 4);
    atomicAdd(&den1[d * 4 + 0], expf(leaky(a.x + b.x) - m.x));
    atomicAdd(&den1[d * 4 + 1], expf(leaky(a.y + b.y) - m.y));
    atomicAdd(&den1[d * 4 + 2], expf(leaky(a.z + b.z) - m.z));
    atomicAdd(&den1[d * 4 + 3], expf(leaky(a.w + b.w) - m.w));
}

// out1[dst, c] += h1[src, c] * w(e, head(c)); thread per (edge, channel)
__global__ void k_agg1(const int* __restrict__ src, const int* __restrict__ dst, int E, int N,
                       const float* __restrict__ ssrc, const float* __restrict__ sdst,
                       const float* __restrict__ m1, const float* __restrict__ den1,
                       const float* __restrict__ h1, float* __restrict__ out1) {
    long long idx = blockIdx.x * (long long)blockDim.x + threadIdx.x;
    long long tot = (long long)(E + N) * 64;
    if (idx >= tot) return;
    int e = (int)(idx >> 6);
    int c = (int)(idx & 63);
    int s, d;
    if (e < E) { s = src[e]; d = dst[e]; } else { s = d = e - E; }
    int hd = c >> 4;
    float al = leaky(ssrc[s * 4 + hd] + sdst[d * 4 + hd]);
    float w = expf(al - m1[d * 4 + hd]) / (den1[d * 4 + hd] + 1e-16f);
    atomicAdd(&out1[(size_t)d * 64 + c], h1[(size_t)s * 64 + c] * w);
}

// act = elu(acc + bias), in place; C = channels
__global__ void k_bias_elu(float* __restrict__ acc, const float* __restrict__ bias, int N, int C) {
    long long i = blockIdx.x * (long long)blockDim.x + threadIdx.x;
    if (i >= (long long)N * C) return;
    float v = acc[i] + bias[i % C];
    acc[i] = v > 0.f ? v : expm1f(v);
}

// h2 = act1 @ W2  [N,64]@[64,256]; 8 nodes per block, 256 threads (one output col each)
__global__ void k_h2(const float* __restrict__ act1, const float* __restrict__ W2,
                     float* __restrict__ h2, int N) {
    __shared__ float sx[8][64];
    int n0 = blockIdx.x * 8;
    int t = threadIdx.x;
    for (int i = t; i < 8 * 64; i += 256) {
        int nn = n0 + (i >> 6);
        sx[i >> 6][i & 63] = (nn < N) ? act1[(size_t)nn * 64 + (i & 63)] : 0.f;
    }
    __syncthreads();
    float acc[8];
#pragma unroll
    for (int j = 0; j < 8; ++j) acc[j] = 0.f;
    for (int k = 0; k < 64; ++k) {
        float w = W2[(size_t)k * 256 + t];
#pragma unroll
        for (int j = 0; j < 8; ++j) acc[j] += sx[j][k] * w;
    }
#pragma unroll
    for (int j = 0; j < 8; ++j) {
        int nn = n0 + j;
        if (nn < N) h2[(size_t)nn * 256 + t] = acc[j];
    }
}

// layer2 scores (H=1): s_src2[n] = sum_c h2[n,c]*a_src2[c]; block per node
__global__ void k_s2(const float* __restrict__ h2, const float* __restrict__ a_src,
                     const float* __restrict__ a_dst, float* __restrict__ ssrc,
                     float* __restrict__ sdst, int N) {
    __shared__ float red[8];
    int n = blockIdx.x;
    int t = threadIdx.x;
    float v = h2[(size_t)n * 256 + t];
    float vs = v * a_src[t];
    float vd = v * a_dst[t];
#pragma unroll
    for (int off = 32; off >= 1; off >>= 1) {
        vs += __shfl_xor(vs, off);
        vd += __shfl_xor(vd, off);
    }
    int wave = t >> 6, lane = t & 63;
    if (lane == 0) { red[wave] = vs; red[4 + wave] = vd; }
    __syncthreads();
    if (t == 0) ssrc[n] = red[0] + red[1] + red[2] + red[3];
    if (t == 1) sdst[n] = red[4] + red[5] + red[6] + red[7];
}

__global__ void k_max2(const int* __restrict__ src, const int* __restrict__ dst, int E, int N,
                       const float* __restrict__ ssrc, const float* __restrict__ sdst,
                       float* __restrict__ m2) {
    int e = blockIdx.x * blockDim.x + threadIdx.x;
    if (e >= E + N) return;
    int s, d;
    if (e < E) { s = src[e]; d = dst[e]; } else { s = d = e - E; }
    atomicMaxF(&m2[d], leaky(ssrc[s] + sdst[d]));
}

__global__ void k_den2(const int* __restrict__ src, const int* __restrict__ dst, int E, int N,
                       const float* __restrict__ ssrc, const float* __restrict__ sdst,
                       const float* __restrict__ m2, float* __restrict__ den2) {
    int e = blockIdx.x * blockDim.x + threadIdx.x;
    if (e >= E + N) return;
    int s, d;
    if (e < E) { s = src[e]; d = dst[e]; } else { s = d = e - E; }
    atomicAdd(&den2[d], expf(leaky(ssrc[s] + sdst[d]) - m2[d]));
}

// out2[dst, 0:256] += h2[src, 0:256] * w; block per edge
__global__ void k_agg2(const int* __restrict__ src, const int* __restrict__ dst, int E, int N,
                       const float* __restrict__ ssrc, const float* __restrict__ sdst,
                       const float* __restrict__ m2, const float* __restrict__ den2,
                       const float* __restrict__ h2, float* __restrict__ out2) {
    int e = blockIdx.x;
    int s, d;
    if (e < E) { s = src[e]; d = dst[e]; } else { s = d = e - E; }
    float al = leaky(ssrc[s] + sdst[d]);
    float w = expf(al - m2[d]) / (den2[d] + 1e-16f);
    int t = threadIdx.x;
    atomicAdd(&out2[(size_t)d * 256 + t], h2[(size_t)s * 256 + t] * w);
}

// per-graph max pool; batch is sorted. block per graph, thread per channel
__global__ void k_pool(const float* __restrict__ act2, const int* __restrict__ batch, int N,
                       float* __restrict__ pooled) {
    int g = blockIdx.x;
    int t = threadIdx.x;
    int lo = 0, hi = N;
    while (lo < hi) { int mid = (lo + hi) >> 1; if (batch[mid] < g) lo = mid + 1; else hi = mid; }
    int start = lo;
    lo = start; hi = N;
    while (lo < hi) { int mid = (lo + hi) >> 1; if (batch[mid] < g + 1) lo = mid + 1; else hi = mid; }
    int end = lo;
    float m = -INFINITY;
    for (int n = start; n < end; ++n) m = fmaxf(m, act2[(size_t)n * 256 + t]);
    pooled[g * 256 + t] = m;
}

// out = act(A @ W + b); thread per output element
__global__ void k_lin(const float* __restrict__ A, const float* __restrict__ W,
                      const float* __restrict__ b, float* __restrict__ out,
                      int M, int K, int Nc, int do_relu) {
    int idx = blockIdx.x * blockDim.x + threadIdx.x;
    if (idx >= M * Nc) return;
    int i = idx / Nc, j = idx % Nc;
    float acc = b[j];
    for (int k = 0; k < K; ++k) acc += A[(size_t)i * K + k] * W[(size_t)k * Nc + j];
    if (do_relu) acc = fmaxf(acc, 0.f);
    out[idx] = acc;
}

extern "C" void kernel_launch(void* const* d_in, const int* in_sizes, int n_in,
                              void* d_out, int out_size, void* d_ws, size_t ws_size,
                              hipStream_t stream) {
    const float* x      = (const float*)d_in[0];
    const int*   ei     = (const int*)d_in[1];
    const int*   batch  = (const int*)d_in[2];
    const float* W1     = (const float*)d_in[3];
    const float* a_src1 = (const float*)d_in[4];
    const float* a_dst1 = (const float*)d_in[5];
    const float* b1     = (const float*)d_in[6];
    const float* W2     = (const float*)d_in[7];
    const float* a_src2 = (const float*)d_in[8];
    const float* a_dst2 = (const float*)d_in[9];
    const float* b2     = (const float*)d_in[10];
    const float* Wl1    = (const float*)d_in[11];
    const float* bl1    = (const float*)d_in[12];
    const float* Wl2    = (const float*)d_in[13];
    const float* bl2    = (const float*)d_in[14];
    const float* Wl3    = (const float*)d_in[15];
    const float* bl3    = (const float*)d_in[16];

    const int N = in_sizes[0] / 27;   // 50000
    const int E = in_sizes[1] / 2;    // 800000
    const int G = out_size / 4;       // 256
    const int EN = E + N;             // edges incl self loops

    const int* srcA = ei;
    const int* dstA = ei + E;

    float* ws = (float*)d_ws;
    float* h1    = ws; ws += (size_t)N * 64;
    float* ssrc1 = ws; ws += (size_t)N * 4;
    float* sdst1 = ws; ws += (size_t)N * 4;
    float* m1    = ws; ws += (size_t)N * 4;
    float* den1  = ws; ws += (size_t)N * 4;
    float* out1  = ws; ws += (size_t)N * 64;  // becomes act1 in place
    float* h2    = ws; ws += (size_t)N * 256;
    float* ssrc2 = ws; ws += (size_t)N;
    float* sdst2 = ws; ws += (size_t)N;
    float* m2    = ws; ws += (size_t)N;
    float* den2  = ws; ws += (size_t)N;
    float* out2  = ws; ws += (size_t)N * 256; // becomes act2 in place
    float* pooled= ws; ws += (size_t)G * 256;
    float* z1    = ws; ws += (size_t)G * 512;
    float* z2    = ws; ws += (size_t)G * 1024;

    // ---- init accumulators ----
    hipMemsetAsync(den1, 0, (size_t)N * 4 * sizeof(float), stream);
    hipMemsetAsync(out1, 0, (size_t)N * 64 * sizeof(float), stream);
    hipMemsetAsync(den2, 0, (size_t)N * sizeof(float), stream);
    hipMemsetAsync(out2, 0, (size_t)N * 256 * sizeof(float), stream);
    {
        long long n = (long long)N * 4;
        k_fill<<<(int)((n + 255) / 256), 256, 0, stream>>>(m1, n, -INFINITY);
        k_fill<<<(N + 255) / 256, 256, 0, stream>>>(m2, N, -INFINITY);
    }

    // ---- layer 1 ----
    k_h1<<<(N + 3) / 4, 256, 0, stream>>>(x, W1, a_src1, a_dst1, h1, ssrc1, sdst1, N);
    k_max1<<<(EN + 255) / 256, 256, 0, stream>>>(srcA, dstA, E, N, ssrc1, sdst1, m1);
    k_den1<<<(EN + 255) / 256, 256, 0, stream>>>(srcA, dstA, E, N, ssrc1, sdst1, m1, den1);
    {
        long long tot = (long long)EN * 64;
        k_agg1<<<(int)((tot + 255) / 256), 256, 0, stream>>>(srcA, dstA, E, N, ssrc1, sdst1,
                                                             m1, den1, h1, out1);
    }
    {
        long long tot = (long long)N * 64;
        k_bias_elu<<<(int)((tot + 255) / 256), 256, 0, stream>>>(out1, b1, N, 64);
    }

    // ---- layer 2 ----
    k_h2<<<(N + 7) / 8, 256, 0, stream>>>(out1, W2, h2, N);
    k_s2<<<N, 256, 0, stream>>>(h2, a_src2, a_dst2, ssrc2, sdst2, N);
    k_max2<<<(EN + 255) / 256, 256, 0, stream>>>(srcA, dstA, E, N, ssrc2, sdst2, m2);
    k_den2<<<(EN + 255) / 256, 256, 0, stream>>>(srcA, dstA, E, N, ssrc2, sdst2, m2, den2);
    k_agg2<<<EN, 256, 0, stream>>>(srcA, dstA, E, N, ssrc2, sdst2, m2, den2, h2, out2);
    {
        long long tot = (long long)N * 256;
        k_bias_elu<<<(int)((tot + 255) / 256), 256, 0, stream>>>(out2, b2, N, 256);
    }

    // ---- pool + MLP ----
    k_pool<<<G, 256, 0, stream>>>(out2, batch, N, pooled);
    k_lin<<<(G * 512 + 255) / 256, 256, 0, stream>>>(pooled, Wl1, bl1, z1, G, 256, 512, 1);
    k_lin<<<(G * 1024 + 255) / 256, 256, 0, stream>>>(z1, Wl2, bl2, z2, G, 512, 1024, 1);
    k_lin<<<(G * 4 + 255) / 256, 256, 0, stream>>>(z2, Wl3, bl3, (float*)d_out, G, 1024, 4, 0);
}

// Round 2
// 745.691 us; speedup vs baseline: 2.4382x; 2.4382x over previous
//
#include <hip/hip_runtime.h>
#include <math.h>

#define NEG_SLOPE 0.2f
#define SCANB 256

__device__ __forceinline__ float leaky(float x) { return x >= 0.f ? x : NEG_SLOPE * x; }
__device__ __forceinline__ float elu(float x) { return x > 0.f ? x : expm1f(x); }

// ---------------- CSR build ----------------

__global__ void k_hist(const int* __restrict__ src, const int* __restrict__ dst, int E, int N,
                       int* __restrict__ deg) {
    int e = blockIdx.x * blockDim.x + threadIdx.x;
    if (e >= E + N) return;
    int d = (e < E) ? dst[e] : e - E;
    atomicAdd(&deg[d], 1);
}

__global__ void k_scan1(const int* __restrict__ in, int* __restrict__ out,
                        int* __restrict__ bsum, int N) {
    __shared__ int sm[SCANB];
    int i = blockIdx.x * SCANB + threadIdx.x;
    int v = (i < N) ? in[i] : 0;
    sm[threadIdx.x] = v;
    __syncthreads();
    for (int off = 1; off < SCANB; off <<= 1) {
        int t = (threadIdx.x >= off) ? sm[threadIdx.x - off] : 0;
        __syncthreads();
        sm[threadIdx.x] += t;
        __syncthreads();
    }
    if (i < N) out[i] = sm[threadIdx.x] - v;  // exclusive
    if (threadIdx.x == SCANB - 1) bsum[blockIdx.x] = sm[SCANB - 1];
}

__global__ void k_scan2(int* __restrict__ bsum, int nb) {  // one block, exclusive in place
    __shared__ int sm[SCANB];
    int v = (threadIdx.x < nb) ? bsum[threadIdx.x] : 0;
    sm[threadIdx.x] = v;
    __syncthreads();
    for (int off = 1; off < SCANB; off <<= 1) {
        int t = (threadIdx.x >= off) ? sm[threadIdx.x - off] : 0;
        __syncthreads();
        sm[threadIdx.x] += t;
        __syncthreads();
    }
    if (threadIdx.x < nb) bsum[threadIdx.x] = sm[threadIdx.x] - v;
}

__global__ void k_scan3(int* __restrict__ out, const int* __restrict__ bsum, int N) {
    int i = blockIdx.x * SCANB + threadIdx.x;
    if (i < N) out[i] += bsum[blockIdx.x];
}

__global__ void k_scatter(const int* __restrict__ src, const int* __restrict__ dst, int E, int N,
                          int* __restrict__ cursor, int* __restrict__ csr) {
    int e = blockIdx.x * blockDim.x + threadIdx.x;
    if (e >= E + N) return;
    int s, d;
    if (e < E) { s = src[e]; d = dst[e]; } else { s = d = e - E; }
    int pos = atomicAdd(&cursor[d], 1);
    csr[pos] = s;
}

// ---------------- layer 1 ----------------

// h1 = x @ W1  [N,27]@[27,64], plus per-head scores s_src/s_dst [N,4]
__global__ void k_h1(const float* __restrict__ x, const float* __restrict__ W1,
                     const float* __restrict__ a_src, const float* __restrict__ a_dst,
                     float* __restrict__ h1, float* __restrict__ ssrc, float* __restrict__ sdst,
                     int N) {
    __shared__ float sW[27 * 64];
    for (int i = threadIdx.x; i < 27 * 64; i += blockDim.x) sW[i] = W1[i];
    __syncthreads();
    int wave = threadIdx.x >> 6;
    int lane = threadIdx.x & 63;
    int n = blockIdx.x * 4 + wave;
    if (n >= N) return;
    const float* xr = x + (size_t)n * 27;
    float acc = 0.f;
#pragma unroll
    for (int k = 0; k < 27; ++k) acc += xr[k] * sW[k * 64 + lane];
    h1[(size_t)n * 64 + lane] = acc;
    int hd = lane >> 4, c = lane & 15;
    float vs = acc * a_src[hd * 16 + c];
    float vd = acc * a_dst[hd * 16 + c];
#pragma unroll
    for (int off = 8; off >= 1; off >>= 1) {
        vs += __shfl_xor(vs, off);
        vd += __shfl_xor(vd, off);
    }
    if (c == 0) {
        ssrc[n * 4 + hd] = vs;
        sdst[n * 4 + hd] = vd;
    }
}

// gather GAT layer 1: wave per dst node; 4 heads, 64 channels; fused softmax + agg + bias + elu
__global__ void k_gat1(const int* __restrict__ csr, const int* __restrict__ offs,
                       const int* __restrict__ deg,
                       const float* __restrict__ ssrc, const float* __restrict__ sdst,
                       const float* __restrict__ h1, const float* __restrict__ bias,
                       float* __restrict__ out, int N) {
    int wave = threadIdx.x >> 6, lane = threadIdx.x & 63;
    int d = blockIdx.x * 4 + wave;
    if (d >= N) return;
    int start = offs[d], dg = deg[d];
    float4 sd = *(const float4*)(sdst + (size_t)d * 4);

    float m0 = -INFINITY, m1 = -INFINITY, m2 = -INFINITY, m3 = -INFINITY;
    for (int j = lane; j < dg; j += 64) {
        int s = csr[start + j];
        float4 a = *(const float4*)(ssrc + (size_t)s * 4);
        m0 = fmaxf(m0, leaky(a.x + sd.x));
        m1 = fmaxf(m1, leaky(a.y + sd.y));
        m2 = fmaxf(m2, leaky(a.z + sd.z));
        m3 = fmaxf(m3, leaky(a.w + sd.w));
    }
#pragma unroll
    for (int off = 32; off >= 1; off >>= 1) {
        m0 = fmaxf(m0, __shfl_xor(m0, off));
        m1 = fmaxf(m1, __shfl_xor(m1, off));
        m2 = fmaxf(m2, __shfl_xor(m2, off));
        m3 = fmaxf(m3, __shfl_xor(m3, off));
    }
    float e0 = 0.f, e1 = 0.f, e2 = 0.f, e3 = 0.f;
    for (int j = lane; j < dg; j += 64) {
        int s = csr[start + j];
        float4 a = *(const float4*)(ssrc + (size_t)s * 4);
        e0 += expf(leaky(a.x + sd.x) - m0);
        e1 += expf(leaky(a.y + sd.y) - m1);
        e2 += expf(leaky(a.z + sd.z) - m2);
        e3 += expf(leaky(a.w + sd.w) - m3);
    }
#pragma unroll
    for (int off = 32; off >= 1; off >>= 1) {
        e0 += __shfl_xor(e0, off);
        e1 += __shfl_xor(e1, off);
        e2 += __shfl_xor(e2, off);
        e3 += __shfl_xor(e3, off);
    }
    float i0 = 1.f / (e0 + 1e-16f), i1 = 1.f / (e1 + 1e-16f);
    float i2 = 1.f / (e2 + 1e-16f), i3 = 1.f / (e3 + 1e-16f);

    int hd = lane >> 4;
    float mh  = hd == 0 ? m0 : hd == 1 ? m1 : hd == 2 ? m2 : m3;
    float ih  = hd == 0 ? i0 : hd == 1 ? i1 : hd == 2 ? i2 : i3;
    float sdh = hd == 0 ? sd.x : hd == 1 ? sd.y : hd == 2 ? sd.z : sd.w;

    float acc = 0.f;
    for (int j = 0; j < dg; ++j) {
        int s = csr[start + j];
        float w = expf(leaky(ssrc[(size_t)s * 4 + hd] + sdh) - mh) * ih;
        acc += h1[(size_t)s * 64 + lane] * w;
    }
    out[(size_t)d * 64 + lane] = elu(acc + bias[lane]);
}

// ---------------- layer 2 ----------------

// h2 = act1 @ W2  [N,64]@[64,256]; 8 nodes per block, 256 threads (one output col each)
__global__ void k_h2(const float* __restrict__ act1, const float* __restrict__ W2,
                     float* __restrict__ h2, int N) {
    __shared__ float sx[8][64];
    int n0 = blockIdx.x * 8;
    int t = threadIdx.x;
    for (int i = t; i < 8 * 64; i += 256) {
        int nn = n0 + (i >> 6);
        sx[i >> 6][i & 63] = (nn < N) ? act1[(size_t)nn * 64 + (i & 63)] : 0.f;
    }
    __syncthreads();
    float acc[8];
#pragma unroll
    for (int j = 0; j < 8; ++j) acc[j] = 0.f;
    for (int k = 0; k < 64; ++k) {
        float w = W2[(size_t)k * 256 + t];
#pragma unroll
        for (int j = 0; j < 8; ++j) acc[j] += sx[j][k] * w;
    }
#pragma unroll
    for (int j = 0; j < 8; ++j) {
        int nn = n0 + j;
        if (nn < N) h2[(size_t)nn * 256 + t] = acc[j];
    }
}

// layer2 scores (H=1): block per node
__global__ void k_s2(const float* __restrict__ h2, const float* __restrict__ a_src,
                     const float* __restrict__ a_dst, float* __restrict__ ssrc,
                     float* __restrict__ sdst, int N) {
    __shared__ float red[8];
    int n = blockIdx.x;
    int t = threadIdx.x;
    float v = h2[(size_t)n * 256 + t];
    float vs = v * a_src[t];
    float vd = v * a_dst[t];
#pragma unroll
    for (int off = 32; off >= 1; off >>= 1) {
        vs += __shfl_xor(vs, off);
        vd += __shfl_xor(vd, off);
    }
    int wave = t >> 6, lane = t & 63;
    if (lane == 0) { red[wave] = vs; red[4 + wave] = vd; }
    __syncthreads();
    if (t == 0) ssrc[n] = red[0] + red[1] + red[2] + red[3];
    if (t == 1) sdst[n] = red[4] + red[5] + red[6] + red[7];
}

// gather GAT layer 2: wave per dst node; H=1, 256 channels (float4 per lane)
__global__ void k_gat2(const int* __restrict__ csr, const int* __restrict__ offs,
                       const int* __restrict__ deg,
                       const float* __restrict__ ssrc, const float* __restrict__ sdst,
                       const float* __restrict__ h2, const float* __restrict__ bias,
                       float* __restrict__ out, int N) {
    int wave = threadIdx.x >> 6, lane = threadIdx.x & 63;
    int d = blockIdx.x * 4 + wave;
    if (d >= N) return;
    int start = offs[d], dg = deg[d];
    float sd = sdst[d];

    float m = -INFINITY;
    for (int j = lane; j < dg; j += 64)
        m = fmaxf(m, leaky(ssrc[csr[start + j]] + sd));
#pragma unroll
    for (int off = 32; off >= 1; off >>= 1) m = fmaxf(m, __shfl_xor(m, off));

    float den = 0.f;
    for (int j = lane; j < dg; j += 64)
        den += expf(leaky(ssrc[csr[start + j]] + sd) - m);
#pragma unroll
    for (int off = 32; off >= 1; off >>= 1) den += __shfl_xor(den, off);
    float inv = 1.f / (den + 1e-16f);

    float4 acc = {0.f, 0.f, 0.f, 0.f};
    for (int j = 0; j < dg; ++j) {
        int s = csr[start + j];
        float w = expf(leaky(ssrc[s] + sd) - m) * inv;
        float4 hv = *(const float4*)(h2 + (size_t)s * 256 + lane * 4);
        acc.x += hv.x * w;
        acc.y += hv.y * w;
        acc.z += hv.z * w;
        acc.w += hv.w * w;
    }
    float4 b = *(const float4*)(bias + lane * 4);
    float4 o;
    o.x = elu(acc.x + b.x);
    o.y = elu(acc.y + b.y);
    o.z = elu(acc.z + b.z);
    o.w = elu(acc.w + b.w);
    *(float4*)(out + (size_t)d * 256 + lane * 4) = o;
}

// ---------------- pool + MLP ----------------

__global__ void k_pool(const float* __restrict__ act2, const int* __restrict__ batch, int N,
                       float* __restrict__ pooled) {
    int g = blockIdx.x;
    int t = threadIdx.x;
    int lo = 0, hi = N;
    while (lo < hi) { int mid = (lo + hi) >> 1; if (batch[mid] < g) lo = mid + 1; else hi = mid; }
    int start = lo;
    lo = start; hi = N;
    while (lo < hi) { int mid = (lo + hi) >> 1; if (batch[mid] < g + 1) lo = mid + 1; else hi = mid; }
    int end = lo;
    float m = -INFINITY;
    for (int n = start; n < end; ++n) m = fmaxf(m, act2[(size_t)n * 256 + t]);
    pooled[g * 256 + t] = m;
}

__global__ void k_lin(const float* __restrict__ A, const float* __restrict__ W,
                      const float* __restrict__ b, float* __restrict__ out,
                      int M, int K, int Nc, int do_relu) {
    int idx = blockIdx.x * blockDim.x + threadIdx.x;
    if (idx >= M * Nc) return;
    int i = idx / Nc, j = idx % Nc;
    float acc = b[j];
    for (int k = 0; k < K; ++k) acc += A[(size_t)i * K + k] * W[(size_t)k * Nc + j];
    if (do_relu) acc = fmaxf(acc, 0.f);
    out[idx] = acc;
}

extern "C" void kernel_launch(void* const* d_in, const int* in_sizes, int n_in,
                              void* d_out, int out_size, void* d_ws, size_t ws_size,
                              hipStream_t stream) {
    const float* x      = (const float*)d_in[0];
    const int*   ei     = (const int*)d_in[1];
    const int*   batch  = (const int*)d_in[2];
    const float* W1     = (const float*)d_in[3];
    const float* a_src1 = (const float*)d_in[4];
    const float* a_dst1 = (const float*)d_in[5];
    const float* b1     = (const float*)d_in[6];
    const float* W2     = (const float*)d_in[7];
    const float* a_src2 = (const float*)d_in[8];
    const float* a_dst2 = (const float*)d_in[9];
    const float* b2     = (const float*)d_in[10];
    const float* Wl1    = (const float*)d_in[11];
    const float* bl1    = (const float*)d_in[12];
    const float* Wl2    = (const float*)d_in[13];
    const float* bl2    = (const float*)d_in[14];
    const float* Wl3    = (const float*)d_in[15];
    const float* bl3    = (const float*)d_in[16];

    const int N = in_sizes[0] / 27;   // 50000
    const int E = in_sizes[1] / 2;    // 800000
    const int G = out_size / 4;       // 256
    const int EN = E + N;

    const int* srcA = ei;
    const int* dstA = ei + E;

    // ---- workspace layout (ints first, then floats) ----
    char* wp = (char*)d_ws;
    int* deg    = (int*)wp; wp += (size_t)N * 4;
    int* offs   = (int*)wp; wp += (size_t)N * 4;
    int* cursor = (int*)wp; wp += (size_t)N * 4;
    int* bsum   = (int*)wp; wp += (size_t)SCANB * 4;
    int* csr    = (int*)wp; wp += (size_t)EN * 4;

    float* h1    = (float*)wp; wp += (size_t)N * 64 * 4;
    float* ssrc1 = (float*)wp; wp += (size_t)N * 4 * 4;
    float* sdst1 = (float*)wp; wp += (size_t)N * 4 * 4;
    float* act1  = (float*)wp; wp += (size_t)N * 64 * 4;
    float* h2    = (float*)wp; wp += (size_t)N * 256 * 4;
    float* ssrc2 = (float*)wp; wp += (size_t)N * 4;
    float* sdst2 = (float*)wp; wp += (size_t)N * 4;
    float* act2  = (float*)wp; wp += (size_t)N * 256 * 4;
    float* pooled= (float*)wp; wp += (size_t)G * 256 * 4;
    float* z1    = (float*)wp; wp += (size_t)G * 512 * 4;
    float* z2    = (float*)wp; wp += (size_t)G * 1024 * 4;

    const int nb = (N + SCANB - 1) / SCANB;  // 196 <= 256

    // ---- CSR build (shared by both layers) ----
    hipMemsetAsync(deg, 0, (size_t)N * 4, stream);
    k_hist<<<(EN + 255) / 256, 256, 0, stream>>>(srcA, dstA, E, N, deg);
    k_scan1<<<nb, SCANB, 0, stream>>>(deg, offs, bsum, N);
    k_scan2<<<1, SCANB, 0, stream>>>(bsum, nb);
    k_scan3<<<nb, SCANB, 0, stream>>>(offs, bsum, N);
    hipMemcpyAsync(cursor, offs, (size_t)N * 4, hipMemcpyDeviceToDevice, stream);
    k_scatter<<<(EN + 255) / 256, 256, 0, stream>>>(srcA, dstA, E, N, cursor, csr);

    // ---- layer 1 ----
    k_h1<<<(N + 3) / 4, 256, 0, stream>>>(x, W1, a_src1, a_dst1, h1, ssrc1, sdst1, N);
    k_gat1<<<(N + 3) / 4, 256, 0, stream>>>(csr, offs, deg, ssrc1, sdst1, h1, b1, act1, N);

    // ---- layer 2 ----
    k_h2<<<(N + 7) / 8, 256, 0, stream>>>(act1, W2, h2, N);
    k_s2<<<N, 256, 0, stream>>>(h2, a_src2, a_dst2, ssrc2, sdst2, N);
    k_gat2<<<(N + 3) / 4, 256, 0, stream>>>(csr, offs, deg, ssrc2, sdst2, h2, b2, act2, N);

    // ---- pool + MLP ----
    k_pool<<<G, 256, 0, stream>>>(act2, batch, N, pooled);
    k_lin<<<(G * 512 + 255) / 256, 256, 0, stream>>>(pooled, Wl1, bl1, z1, G, 256, 512, 1);
    k_lin<<<(G * 1024 + 255) / 256, 256, 0, stream>>>(z1, Wl2, bl2, z2, G, 512, 1024, 1);
    k_lin<<<(G * 4 + 255) / 256, 256, 0, stream>>>(z2, Wl3, bl3, (float*)d_out, G, 1024, 4, 0);
}

// Round 3
// 546.367 us; speedup vs baseline: 3.3277x; 1.3648x over previous
//
#include <hip/hip_runtime.h>
#include <math.h>

#define NEG_SLOPE 0.2f
#define SCANB 256
#define GPB 2   // graphs per block in fused MLP

__device__ __forceinline__ float leaky(float x) { return x >= 0.f ? x : NEG_SLOPE * x; }
__device__ __forceinline__ float elu(float x) { return x > 0.f ? x : expm1f(x); }

// ---------------- CSR build ----------------

__global__ void k_hist(const int* __restrict__ src, const int* __restrict__ dst, int E, int N,
                       int* __restrict__ deg) {
    int e = blockIdx.x * blockDim.x + threadIdx.x;
    if (e >= E + N) return;
    int d = (e < E) ? dst[e] : e - E;
    atomicAdd(&deg[d], 1);
}

__global__ void k_scan1(const int* __restrict__ in, int* __restrict__ out,
                        int* __restrict__ bsum, int N) {
    __shared__ int sm[SCANB];
    int i = blockIdx.x * SCANB + threadIdx.x;
    int v = (i < N) ? in[i] : 0;
    sm[threadIdx.x] = v;
    __syncthreads();
    for (int off = 1; off < SCANB; off <<= 1) {
        int t = (threadIdx.x >= off) ? sm[threadIdx.x - off] : 0;
        __syncthreads();
        sm[threadIdx.x] += t;
        __syncthreads();
    }
    if (i < N) out[i] = sm[threadIdx.x] - v;  // exclusive
    if (threadIdx.x == SCANB - 1) bsum[blockIdx.x] = sm[SCANB - 1];
}

__global__ void k_scan2(int* __restrict__ bsum, int nb) {  // one block, exclusive in place
    __shared__ int sm[SCANB];
    int v = (threadIdx.x < nb) ? bsum[threadIdx.x] : 0;
    sm[threadIdx.x] = v;
    __syncthreads();
    for (int off = 1; off < SCANB; off <<= 1) {
        int t = (threadIdx.x >= off) ? sm[threadIdx.x - off] : 0;
        __syncthreads();
        sm[threadIdx.x] += t;
        __syncthreads();
    }
    if (threadIdx.x < nb) bsum[threadIdx.x] = sm[threadIdx.x] - v;
}

__global__ void k_scan3(int* __restrict__ out, const int* __restrict__ bsum, int N) {
    int i = blockIdx.x * SCANB + threadIdx.x;
    if (i < N) out[i] += bsum[blockIdx.x];
}

__global__ void k_scatter(const int* __restrict__ src, const int* __restrict__ dst, int E, int N,
                          int* __restrict__ cursor, int* __restrict__ csr) {
    int e = blockIdx.x * blockDim.x + threadIdx.x;
    if (e >= E + N) return;
    int s, d;
    if (e < E) { s = src[e]; d = dst[e]; } else { s = d = e - E; }
    int pos = atomicAdd(&cursor[d], 1);
    csr[pos] = s;
}

// ---------------- layer 1 ----------------

// h1 = x @ W1  [N,27]@[27,64], plus per-head scores s_src/s_dst [N,4]
__global__ void k_h1(const float* __restrict__ x, const float* __restrict__ W1,
                     const float* __restrict__ a_src, const float* __restrict__ a_dst,
                     float* __restrict__ h1, float* __restrict__ ssrc, float* __restrict__ sdst,
                     int N) {
    __shared__ float sW[27 * 64];
    for (int i = threadIdx.x; i < 27 * 64; i += blockDim.x) sW[i] = W1[i];
    __syncthreads();
    int wave = threadIdx.x >> 6;
    int lane = threadIdx.x & 63;
    int n = blockIdx.x * 4 + wave;
    if (n >= N) return;
    const float* xr = x + (size_t)n * 27;
    float acc = 0.f;
#pragma unroll
    for (int k = 0; k < 27; ++k) acc += xr[k] * sW[k * 64 + lane];
    h1[(size_t)n * 64 + lane] = acc;
    int hd = lane >> 4, c = lane & 15;
    float vs = acc * a_src[hd * 16 + c];
    float vd = acc * a_dst[hd * 16 + c];
#pragma unroll
    for (int off = 8; off >= 1; off >>= 1) {
        vs += __shfl_xor(vs, off);
        vd += __shfl_xor(vd, off);
    }
    if (c == 0) {
        ssrc[n * 4 + hd] = vs;
        sdst[n * 4 + hd] = vd;
    }
}

// gather GAT layer 1: wave per dst node; 4 heads, 64 channels; fused softmax + agg + bias + elu
__global__ void k_gat1(const int* __restrict__ csr, const int* __restrict__ offs,
                       const int* __restrict__ deg,
                       const float* __restrict__ ssrc, const float* __restrict__ sdst,
                       const float* __restrict__ h1, const float* __restrict__ bias,
                       float* __restrict__ out, int N) {
    int wave = threadIdx.x >> 6, lane = threadIdx.x & 63;
    int d = blockIdx.x * 4 + wave;
    if (d >= N) return;
    int start = offs[d], dg = deg[d];
    float4 sd = *(const float4*)(sdst + (size_t)d * 4);

    float m0 = -INFINITY, m1 = -INFINITY, m2 = -INFINITY, m3 = -INFINITY;
    for (int j = lane; j < dg; j += 64) {
        int s = csr[start + j];
        float4 a = *(const float4*)(ssrc + (size_t)s * 4);
        m0 = fmaxf(m0, leaky(a.x + sd.x));
        m1 = fmaxf(m1, leaky(a.y + sd.y));
        m2 = fmaxf(m2, leaky(a.z + sd.z));
        m3 = fmaxf(m3, leaky(a.w + sd.w));
    }
#pragma unroll
    for (int off = 32; off >= 1; off >>= 1) {
        m0 = fmaxf(m0, __shfl_xor(m0, off));
        m1 = fmaxf(m1, __shfl_xor(m1, off));
        m2 = fmaxf(m2, __shfl_xor(m2, off));
        m3 = fmaxf(m3, __shfl_xor(m3, off));
    }
    float e0 = 0.f, e1 = 0.f, e2 = 0.f, e3 = 0.f;
    for (int j = lane; j < dg; j += 64) {
        int s = csr[start + j];
        float4 a = *(const float4*)(ssrc + (size_t)s * 4);
        e0 += expf(leaky(a.x + sd.x) - m0);
        e1 += expf(leaky(a.y + sd.y) - m1);
        e2 += expf(leaky(a.z + sd.z) - m2);
        e3 += expf(leaky(a.w + sd.w) - m3);
    }
#pragma unroll
    for (int off = 32; off >= 1; off >>= 1) {
        e0 += __shfl_xor(e0, off);
        e1 += __shfl_xor(e1, off);
        e2 += __shfl_xor(e2, off);
        e3 += __shfl_xor(e3, off);
    }
    float i0 = 1.f / (e0 + 1e-16f), i1 = 1.f / (e1 + 1e-16f);
    float i2 = 1.f / (e2 + 1e-16f), i3 = 1.f / (e3 + 1e-16f);

    int hd = lane >> 4;
    float mh  = hd == 0 ? m0 : hd == 1 ? m1 : hd == 2 ? m2 : m3;
    float ih  = hd == 0 ? i0 : hd == 1 ? i1 : hd == 2 ? i2 : i3;
    float sdh = hd == 0 ? sd.x : hd == 1 ? sd.y : hd == 2 ? sd.z : sd.w;

    float acc = 0.f;
    for (int j = 0; j < dg; ++j) {
        int s = csr[start + j];
        float w = expf(leaky(ssrc[(size_t)s * 4 + hd] + sdh) - mh) * ih;
        acc += h1[(size_t)s * 64 + lane] * w;
    }
    out[(size_t)d * 64 + lane] = elu(acc + bias[lane]);
}

// ---------------- layer 2 ----------------

// h2 = act1 @ W2  [N,64]@[64,256]; 8 nodes per block, 256 threads (one output col each)
__global__ void k_h2(const float* __restrict__ act1, const float* __restrict__ W2,
                     float* __restrict__ h2, int N) {
    __shared__ float sx[8][64];
    int n0 = blockIdx.x * 8;
    int t = threadIdx.x;
    for (int i = t; i < 8 * 64; i += 256) {
        int nn = n0 + (i >> 6);
        sx[i >> 6][i & 63] = (nn < N) ? act1[(size_t)nn * 64 + (i & 63)] : 0.f;
    }
    __syncthreads();
    float acc[8];
#pragma unroll
    for (int j = 0; j < 8; ++j) acc[j] = 0.f;
    for (int k = 0; k < 64; ++k) {
        float w = W2[(size_t)k * 256 + t];
#pragma unroll
        for (int j = 0; j < 8; ++j) acc[j] += sx[j][k] * w;
    }
#pragma unroll
    for (int j = 0; j < 8; ++j) {
        int nn = n0 + j;
        if (nn < N) h2[(size_t)nn * 256 + t] = acc[j];
    }
}

// layer2 scores (H=1): block per node
__global__ void k_s2(const float* __restrict__ h2, const float* __restrict__ a_src,
                     const float* __restrict__ a_dst, float* __restrict__ ssrc,
                     float* __restrict__ sdst, int N) {
    __shared__ float red[8];
    int n = blockIdx.x;
    int t = threadIdx.x;
    float v = h2[(size_t)n * 256 + t];
    float vs = v * a_src[t];
    float vd = v * a_dst[t];
#pragma unroll
    for (int off = 32; off >= 1; off >>= 1) {
        vs += __shfl_xor(vs, off);
        vd += __shfl_xor(vd, off);
    }
    int wave = t >> 6, lane = t & 63;
    if (lane == 0) { red[wave] = vs; red[4 + wave] = vd; }
    __syncthreads();
    if (t == 0) ssrc[n] = red[0] + red[1] + red[2] + red[3];
    if (t == 1) sdst[n] = red[4] + red[5] + red[6] + red[7];
}

// gather GAT layer 2: wave per dst node; H=1, 256 channels (float4 per lane)
__global__ void k_gat2(const int* __restrict__ csr, const int* __restrict__ offs,
                       const int* __restrict__ deg,
                       const float* __restrict__ ssrc, const float* __restrict__ sdst,
                       const float* __restrict__ h2, const float* __restrict__ bias,
                       float* __restrict__ out, int N) {
    int wave = threadIdx.x >> 6, lane = threadIdx.x & 63;
    int d = blockIdx.x * 4 + wave;
    if (d >= N) return;
    int start = offs[d], dg = deg[d];
    float sd = sdst[d];

    float m = -INFINITY;
    for (int j = lane; j < dg; j += 64)
        m = fmaxf(m, leaky(ssrc[csr[start + j]] + sd));
#pragma unroll
    for (int off = 32; off >= 1; off >>= 1) m = fmaxf(m, __shfl_xor(m, off));

    float den = 0.f;
    for (int j = lane; j < dg; j += 64)
        den += expf(leaky(ssrc[csr[start + j]] + sd) - m);
#pragma unroll
    for (int off = 32; off >= 1; off >>= 1) den += __shfl_xor(den, off);
    float inv = 1.f / (den + 1e-16f);

    float4 acc = {0.f, 0.f, 0.f, 0.f};
    for (int j = 0; j < dg; ++j) {
        int s = csr[start + j];
        float w = expf(leaky(ssrc[s] + sd) - m) * inv;
        float4 hv = *(const float4*)(h2 + (size_t)s * 256 + lane * 4);
        acc.x += hv.x * w;
        acc.y += hv.y * w;
        acc.z += hv.z * w;
        acc.w += hv.w * w;
    }
    float4 b = *(const float4*)(bias + lane * 4);
    float4 o;
    o.x = elu(acc.x + b.x);
    o.y = elu(acc.y + b.y);
    o.z = elu(acc.z + b.z);
    o.w = elu(acc.w + b.w);
    *(float4*)(out + (size_t)d * 256 + lane * 4) = o;
}

// ---------------- pool + fused MLP ----------------

__global__ void k_pool(const float* __restrict__ act2, const int* __restrict__ batch, int N,
                       float* __restrict__ pooled) {
    int g = blockIdx.x;
    int t = threadIdx.x;
    int lo = 0, hi = N;
    while (lo < hi) { int mid = (lo + hi) >> 1; if (batch[mid] < g) lo = mid + 1; else hi = mid; }
    int start = lo;
    lo = start; hi = N;
    while (lo < hi) { int mid = (lo + hi) >> 1; if (batch[mid] < g + 1) lo = mid + 1; else hi = mid; }
    int end = lo;
    float m = -INFINITY;
    for (int n = start; n < end; ++n) m = fmaxf(m, act2[(size_t)n * 256 + t]);
    pooled[g * 256 + t] = m;
}

// whole MLP per GPB graphs in one block: pooled[256] -> relu(512) -> relu(1024) -> 4
__global__ void k_mlp(const float* __restrict__ pooled,
                      const float* __restrict__ Wl1, const float* __restrict__ bl1,
                      const float* __restrict__ Wl2, const float* __restrict__ bl2,
                      const float* __restrict__ Wl3, const float* __restrict__ bl3,
                      float* __restrict__ out, int G) {
    __shared__ float sP[GPB][256];
    __shared__ float sZ1[GPB][512];
    __shared__ float sZ2[GPB][1024];
    __shared__ float sRed[4][GPB][4];
    int t = threadIdx.x;
    int g0 = blockIdx.x * GPB;
#pragma unroll
    for (int g = 0; g < GPB; ++g) sP[g][t] = pooled[(size_t)(g0 + g) * 256 + t];
    __syncthreads();

    // phase 1: [GPB,256] @ [256,512]
    {
        float a00 = 0.f, a01 = 0.f, a10 = 0.f, a11 = 0.f;
#pragma unroll 4
        for (int k = 0; k < 256; ++k) {
            float w0 = Wl1[k * 512 + t];
            float w1 = Wl1[k * 512 + t + 256];
            float p0 = sP[0][k];
            float p1 = sP[1][k];
            a00 += p0 * w0; a01 += p0 * w1;
            a10 += p1 * w0; a11 += p1 * w1;
        }
        float b0 = bl1[t], b1 = bl1[t + 256];
        sZ1[0][t]       = fmaxf(a00 + b0, 0.f);
        sZ1[0][t + 256] = fmaxf(a01 + b1, 0.f);
        sZ1[1][t]       = fmaxf(a10 + b0, 0.f);
        sZ1[1][t + 256] = fmaxf(a11 + b1, 0.f);
    }
    __syncthreads();

    // phase 2: [GPB,512] @ [512,1024]
    {
        float acc[GPB][4];
#pragma unroll
        for (int g = 0; g < GPB; ++g)
#pragma unroll
            for (int c = 0; c < 4; ++c) acc[g][c] = 0.f;
#pragma unroll 4
        for (int k = 0; k < 512; ++k) {
            float w0 = Wl2[k * 1024 + t];
            float w1 = Wl2[k * 1024 + t + 256];
            float w2 = Wl2[k * 1024 + t + 512];
            float w3 = Wl2[k * 1024 + t + 768];
            float z0 = sZ1[0][k];
            float z1 = sZ1[1][k];
            acc[0][0] += z0 * w0; acc[0][1] += z0 * w1; acc[0][2] += z0 * w2; acc[0][3] += z0 * w3;
            acc[1][0] += z1 * w0; acc[1][1] += z1 * w1; acc[1][2] += z1 * w2; acc[1][3] += z1 * w3;
        }
#pragma unroll
        for (int g = 0; g < GPB; ++g)
#pragma unroll
            for (int c = 0; c < 4; ++c)
                sZ2[g][t + c * 256] = fmaxf(acc[g][c] + bl2[t + c * 256], 0.f);
    }
    __syncthreads();

    // phase 3: [GPB,1024] @ [1024,4], split-K over threads
    {
        float pr[GPB][4];
#pragma unroll
        for (int g = 0; g < GPB; ++g)
#pragma unroll
            for (int c = 0; c < 4; ++c) pr[g][c] = 0.f;
#pragma unroll
        for (int kk = 0; kk < 4; ++kk) {
            int k = t + kk * 256;
            float4 w = ((const float4*)Wl3)[k];
            float z0 = sZ2[0][k];
            float z1 = sZ2[1][k];
            pr[0][0] += z0 * w.x; pr[0][1] += z0 * w.y; pr[0][2] += z0 * w.z; pr[0][3] += z0 * w.w;
            pr[1][0] += z1 * w.x; pr[1][1] += z1 * w.y; pr[1][2] += z1 * w.z; pr[1][3] += z1 * w.w;
        }
        int wave = t >> 6, lane = t & 63;
#pragma unroll
        for (int g = 0; g < GPB; ++g)
#pragma unroll
            for (int c = 0; c < 4; ++c) {
                float v = pr[g][c];
#pragma unroll
                for (int off = 32; off >= 1; off >>= 1) v += __shfl_xor(v, off);
                if (lane == 0) sRed[wave][g][c] = v;
            }
        __syncthreads();
        if (t < GPB * 4) {
            int g = t >> 2, c = t & 3;
            float v = sRed[0][g][c] + sRed[1][g][c] + sRed[2][g][c] + sRed[3][g][c];
            out[(size_t)(g0 + g) * 4 + c] = v + bl3[c];
        }
    }
}

extern "C" void kernel_launch(void* const* d_in, const int* in_sizes, int n_in,
                              void* d_out, int out_size, void* d_ws, size_t ws_size,
                              hipStream_t stream) {
    const float* x      = (const float*)d_in[0];
    const int*   ei     = (const int*)d_in[1];
    const int*   batch  = (const int*)d_in[2];
    const float* W1     = (const float*)d_in[3];
    const float* a_src1 = (const float*)d_in[4];
    const float* a_dst1 = (const float*)d_in[5];
    const float* b1     = (const float*)d_in[6];
    const float* W2     = (const float*)d_in[7];
    const float* a_src2 = (const float*)d_in[8];
    const float* a_dst2 = (const float*)d_in[9];
    const float* b2     = (const float*)d_in[10];
    const float* Wl1    = (const float*)d_in[11];
    const float* bl1    = (const float*)d_in[12];
    const float* Wl2    = (const float*)d_in[13];
    const float* bl2    = (const float*)d_in[14];
    const float* Wl3    = (const float*)d_in[15];
    const float* bl3    = (const float*)d_in[16];

    const int N = in_sizes[0] / 27;   // 50000
    const int E = in_sizes[1] / 2;    // 800000
    const int G = out_size / 4;       // 256
    const int EN = E + N;

    const int* srcA = ei;
    const int* dstA = ei + E;

    // ---- workspace layout (ints first, then floats) ----
    char* wp = (char*)d_ws;
    int* deg    = (int*)wp; wp += (size_t)N * 4;
    int* offs   = (int*)wp; wp += (size_t)N * 4;
    int* cursor = (int*)wp; wp += (size_t)N * 4;
    int* bsum   = (int*)wp; wp += (size_t)SCANB * 4;
    int* csr    = (int*)wp; wp += (size_t)EN * 4;

    float* h1    = (float*)wp; wp += (size_t)N * 64 * 4;
    float* ssrc1 = (float*)wp; wp += (size_t)N * 4 * 4;
    float* sdst1 = (float*)wp; wp += (size_t)N * 4 * 4;
    float* act1  = (float*)wp; wp += (size_t)N * 64 * 4;
    float* h2    = (float*)wp; wp += (size_t)N * 256 * 4;
    float* ssrc2 = (float*)wp; wp += (size_t)N * 4;
    float* sdst2 = (float*)wp; wp += (size_t)N * 4;
    float* act2  = (float*)wp; wp += (size_t)N * 256 * 4;
    float* pooled= (float*)wp; wp += (size_t)G * 256 * 4;

    const int nb = (N + SCANB - 1) / SCANB;  // 196 <= 256

    // ---- CSR build (shared by both layers) ----
    hipMemsetAsync(deg, 0, (size_t)N * 4, stream);
    k_hist<<<(EN + 255) / 256, 256, 0, stream>>>(srcA, dstA, E, N, deg);
    k_scan1<<<nb, SCANB, 0, stream>>>(deg, offs, bsum, N);
    k_scan2<<<1, SCANB, 0, stream>>>(bsum, nb);
    k_scan3<<<nb, SCANB, 0, stream>>>(offs, bsum, N);
    hipMemcpyAsync(cursor, offs, (size_t)N * 4, hipMemcpyDeviceToDevice, stream);
    k_scatter<<<(EN + 255) / 256, 256, 0, stream>>>(srcA, dstA, E, N, cursor, csr);

    // ---- layer 1 ----
    k_h1<<<(N + 3) / 4, 256, 0, stream>>>(x, W1, a_src1, a_dst1, h1, ssrc1, sdst1, N);
    k_gat1<<<(N + 3) / 4, 256, 0, stream>>>(csr, offs, deg, ssrc1, sdst1, h1, b1, act1, N);

    // ---- layer 2 ----
    k_h2<<<(N + 7) / 8, 256, 0, stream>>>(act1, W2, h2, N);
    k_s2<<<N, 256, 0, stream>>>(h2, a_src2, a_dst2, ssrc2, sdst2, N);
    k_gat2<<<(N + 3) / 4, 256, 0, stream>>>(csr, offs, deg, ssrc2, sdst2, h2, b2, act2, N);

    // ---- pool + fused MLP ----
    k_pool<<<G, 256, 0, stream>>>(act2, batch, N, pooled);
    k_mlp<<<G / GPB, 256, 0, stream>>>(pooled, Wl1, bl1, Wl2, bl2, Wl3, bl3, (float*)d_out, G);
}

// Round 4
// 458.441 us; speedup vs baseline: 3.9660x; 1.1918x over previous
//
#include <hip/hip_runtime.h>
#include <hip/hip_fp16.h>
#include <math.h>

#define NEG_SLOPE 0.2f
#define SCANB 256
#define GPB 2   // graphs per block in fused MLP

__device__ __forceinline__ float leaky(float x) { return x >= 0.f ? x : NEG_SLOPE * x; }
__device__ __forceinline__ float elu(float x) { return x > 0.f ? x : expm1f(x); }

struct Half4 { __half2 a, b; };

// ---------------- CSR build ----------------

__global__ void k_hist(const int* __restrict__ src, const int* __restrict__ dst, int E, int N,
                       int* __restrict__ deg) {
    int e = blockIdx.x * blockDim.x + threadIdx.x;
    if (e >= E + N) return;
    int d = (e < E) ? dst[e] : e - E;
    atomicAdd(&deg[d], 1);
}

__global__ void k_scan1(const int* __restrict__ in, int* __restrict__ out,
                        int* __restrict__ bsum, int N) {
    __shared__ int sm[SCANB];
    int i = blockIdx.x * SCANB + threadIdx.x;
    int v = (i < N) ? in[i] : 0;
    sm[threadIdx.x] = v;
    __syncthreads();
    for (int off = 1; off < SCANB; off <<= 1) {
        int t = (threadIdx.x >= off) ? sm[threadIdx.x - off] : 0;
        __syncthreads();
        sm[threadIdx.x] += t;
        __syncthreads();
    }
    if (i < N) out[i] = sm[threadIdx.x] - v;  // exclusive
    if (threadIdx.x == SCANB - 1) bsum[blockIdx.x] = sm[SCANB - 1];
}

__global__ void k_scan2(int* __restrict__ bsum, int nb) {
    __shared__ int sm[SCANB];
    int v = (threadIdx.x < nb) ? bsum[threadIdx.x] : 0;
    sm[threadIdx.x] = v;
    __syncthreads();
    for (int off = 1; off < SCANB; off <<= 1) {
        int t = (threadIdx.x >= off) ? sm[threadIdx.x - off] : 0;
        __syncthreads();
        sm[threadIdx.x] += t;
        __syncthreads();
    }
    if (threadIdx.x < nb) bsum[threadIdx.x] = sm[threadIdx.x] - v;
}

__global__ void k_scan3(int* __restrict__ out, const int* __restrict__ bsum, int N) {
    int i = blockIdx.x * SCANB + threadIdx.x;
    if (i < N) out[i] += bsum[blockIdx.x];
}

__global__ void k_scatter(const int* __restrict__ src, const int* __restrict__ dst, int E, int N,
                          int* __restrict__ cursor, int* __restrict__ csr) {
    int e = blockIdx.x * blockDim.x + threadIdx.x;
    if (e >= E + N) return;
    int s, d;
    if (e < E) { s = src[e]; d = dst[e]; } else { s = d = e - E; }
    int pos = atomicAdd(&cursor[d], 1);
    csr[pos] = s;
}

// ---------------- layer 1 ----------------

// h1 = x @ W1  [N,27]@[27,64] (fp16 out), plus per-head scores s_src/s_dst [N,4] (fp32)
__global__ void k_h1(const float* __restrict__ x, const float* __restrict__ W1,
                     const float* __restrict__ a_src, const float* __restrict__ a_dst,
                     __half* __restrict__ h1h, float* __restrict__ ssrc, float* __restrict__ sdst,
                     int N) {
    __shared__ float sW[27 * 64];
    for (int i = threadIdx.x; i < 27 * 64; i += blockDim.x) sW[i] = W1[i];
    __syncthreads();
    int wave = threadIdx.x >> 6;
    int lane = threadIdx.x & 63;
    int n = blockIdx.x * 4 + wave;
    if (n >= N) return;
    const float* xr = x + (size_t)n * 27;
    float acc = 0.f;
#pragma unroll
    for (int k = 0; k < 27; ++k) acc += xr[k] * sW[k * 64 + lane];
    h1h[(size_t)n * 64 + lane] = __float2half(acc);
    int hd = lane >> 4, c = lane & 15;
    float vs = acc * a_src[hd * 16 + c];
    float vd = acc * a_dst[hd * 16 + c];
#pragma unroll
    for (int off = 8; off >= 1; off >>= 1) {
        vs += __shfl_xor(vs, off);
        vd += __shfl_xor(vd, off);
    }
    if (c == 0) {
        ssrc[n * 4 + hd] = vs;
        sdst[n * 4 + hd] = vd;
    }
}

// gather GAT layer 1: wave per dst node; 4 heads x 16 ch; fused softmax + agg + bias + elu
__global__ void k_gat1(const int* __restrict__ csr, const int* __restrict__ offs,
                       const int* __restrict__ deg,
                       const float* __restrict__ ssrc, const float* __restrict__ sdst,
                       const __half* __restrict__ h1h, const float* __restrict__ bias,
                       float* __restrict__ out, int N) {
    int wave = threadIdx.x >> 6, lane = threadIdx.x & 63;
    int d = blockIdx.x * 4 + wave;
    if (d >= N) return;
    int start = offs[d], dg = deg[d];
    float4 sd = *(const float4*)(sdst + (size_t)d * 4);

    float m0 = -INFINITY, m1 = -INFINITY, m2 = -INFINITY, m3 = -INFINITY;
    for (int j = lane; j < dg; j += 64) {
        int s = csr[start + j];
        float4 a = *(const float4*)(ssrc + (size_t)s * 4);
        m0 = fmaxf(m0, leaky(a.x + sd.x));
        m1 = fmaxf(m1, leaky(a.y + sd.y));
        m2 = fmaxf(m2, leaky(a.z + sd.z));
        m3 = fmaxf(m3, leaky(a.w + sd.w));
    }
#pragma unroll
    for (int off = 32; off >= 1; off >>= 1) {
        m0 = fmaxf(m0, __shfl_xor(m0, off));
        m1 = fmaxf(m1, __shfl_xor(m1, off));
        m2 = fmaxf(m2, __shfl_xor(m2, off));
        m3 = fmaxf(m3, __shfl_xor(m3, off));
    }
    float e0 = 0.f, e1 = 0.f, e2 = 0.f, e3 = 0.f;
    for (int j = lane; j < dg; j += 64) {
        int s = csr[start + j];
        float4 a = *(const float4*)(ssrc + (size_t)s * 4);
        e0 += expf(leaky(a.x + sd.x) - m0);
        e1 += expf(leaky(a.y + sd.y) - m1);
        e2 += expf(leaky(a.z + sd.z) - m2);
        e3 += expf(leaky(a.w + sd.w) - m3);
    }
#pragma unroll
    for (int off = 32; off >= 1; off >>= 1) {
        e0 += __shfl_xor(e0, off);
        e1 += __shfl_xor(e1, off);
        e2 += __shfl_xor(e2, off);
        e3 += __shfl_xor(e3, off);
    }
    float i0 = 1.f / (e0 + 1e-16f), i1 = 1.f / (e1 + 1e-16f);
    float i2 = 1.f / (e2 + 1e-16f), i3 = 1.f / (e3 + 1e-16f);

    int hd = lane >> 4;
    float acc = 0.f;
    for (int j0 = 0; j0 < dg; j0 += 64) {
        int j = j0 + lane;
        int s = 0;
        float w0 = 0.f, w1 = 0.f, w2 = 0.f, w3 = 0.f;
        if (j < dg) {
            s = csr[start + j];
            float4 a = *(const float4*)(ssrc + (size_t)s * 4);
            w0 = expf(leaky(a.x + sd.x) - m0) * i0;
            w1 = expf(leaky(a.y + sd.y) - m1) * i1;
            w2 = expf(leaky(a.z + sd.z) - m2) * i2;
            w3 = expf(leaky(a.w + sd.w) - m3) * i3;
        }
        int cnt = min(64, dg - j0);
        for (int jj = 0; jj < cnt; ++jj) {
            int s2 = __shfl(s, jj);
            float t0 = __shfl(w0, jj), t1 = __shfl(w1, jj);
            float t2 = __shfl(w2, jj), t3 = __shfl(w3, jj);
            float ww = hd == 0 ? t0 : hd == 1 ? t1 : hd == 2 ? t2 : t3;
            acc += __half2float(h1h[(size_t)s2 * 64 + lane]) * ww;
        }
    }
    out[(size_t)d * 64 + lane] = elu(acc + bias[lane]);
}

// ---------------- layer 2 ----------------

// h2 = act1 @ W2 (fp16 out) fused with layer-2 scores; 8 nodes/block, 256 threads
__global__ void k_h2s(const float* __restrict__ act1, const float* __restrict__ W2,
                      const float* __restrict__ a_src, const float* __restrict__ a_dst,
                      __half* __restrict__ h2h, float* __restrict__ ssrc,
                      float* __restrict__ sdst, int N) {
    __shared__ float sx[8][64];
    __shared__ float sred[8][4][2];
    int n0 = blockIdx.x * 8;
    int t = threadIdx.x;
    for (int i = t; i < 8 * 64; i += 256) {
        int nn = n0 + (i >> 6);
        sx[i >> 6][i & 63] = (nn < N) ? act1[(size_t)nn * 64 + (i & 63)] : 0.f;
    }
    __syncthreads();
    float acc[8];
#pragma unroll
    for (int j = 0; j < 8; ++j) acc[j] = 0.f;
#pragma unroll 4
    for (int k = 0; k < 64; ++k) {
        float w = W2[(size_t)k * 256 + t];
#pragma unroll
        for (int j = 0; j < 8; ++j) acc[j] += sx[j][k] * w;
    }
    float sa = a_src[t], sda = a_dst[t];
    int wave = t >> 6, lane = t & 63;
#pragma unroll
    for (int j = 0; j < 8; ++j) {
        int nn = n0 + j;
        if (nn < N) h2h[(size_t)nn * 256 + t] = __float2half(acc[j]);
        float vs = acc[j] * sa;
        float vd = acc[j] * sda;
#pragma unroll
        for (int off = 32; off >= 1; off >>= 1) {
            vs += __shfl_xor(vs, off);
            vd += __shfl_xor(vd, off);
        }
        if (lane == 0) { sred[j][wave][0] = vs; sred[j][wave][1] = vd; }
    }
    __syncthreads();
    if (t < 16) {
        int j = t >> 1, which = t & 1;
        int nn = n0 + j;
        if (nn < N) {
            float v = sred[j][0][which] + sred[j][1][which] + sred[j][2][which] + sred[j][3][which];
            if (which == 0) ssrc[nn] = v; else sdst[nn] = v;
        }
    }
}

// gather GAT layer 2: wave per dst node; H=1, 256 channels (4 halves per lane); fused bias+elu, fp16 out
__global__ void k_gat2(const int* __restrict__ csr, const int* __restrict__ offs,
                       const int* __restrict__ deg,
                       const float* __restrict__ ssrc, const float* __restrict__ sdst,
                       const __half* __restrict__ h2h, const float* __restrict__ bias,
                       __half* __restrict__ act2h, int N) {
    int wave = threadIdx.x >> 6, lane = threadIdx.x & 63;
    int d = blockIdx.x * 4 + wave;
    if (d >= N) return;
    int start = offs[d], dg = deg[d];
    float sd = sdst[d];

    float m = -INFINITY;
    for (int j = lane; j < dg; j += 64)
        m = fmaxf(m, leaky(ssrc[csr[start + j]] + sd));
#pragma unroll
    for (int off = 32; off >= 1; off >>= 1) m = fmaxf(m, __shfl_xor(m, off));

    float den = 0.f;
    for (int j = lane; j < dg; j += 64)
        den += expf(leaky(ssrc[csr[start + j]] + sd) - m);
#pragma unroll
    for (int off = 32; off >= 1; off >>= 1) den += __shfl_xor(den, off);
    float inv = 1.f / (den + 1e-16f);

    float ax = 0.f, ay = 0.f, az = 0.f, aw = 0.f;
    for (int j0 = 0; j0 < dg; j0 += 64) {
        int j = j0 + lane;
        int s = 0;
        float w = 0.f;
        if (j < dg) {
            s = csr[start + j];
            w = expf(leaky(ssrc[s] + sd) - m) * inv;
        }
        int cnt = min(64, dg - j0);
        for (int jj = 0; jj < cnt; ++jj) {
            int s2 = __shfl(s, jj);
            float ww = __shfl(w, jj);
            Half4 hv = *(const Half4*)(h2h + (size_t)s2 * 256 + lane * 4);
            float2 f0 = __half22float2(hv.a);
            float2 f1 = __half22float2(hv.b);
            ax += f0.x * ww;
            ay += f0.y * ww;
            az += f1.x * ww;
            aw += f1.y * ww;
        }
    }
    float4 b = *(const float4*)(bias + lane * 4);
    Half4 o;
    o.a = __floats2half2_rn(elu(ax + b.x), elu(ay + b.y));
    o.b = __floats2half2_rn(elu(az + b.z), elu(aw + b.w));
    *(Half4*)(act2h + (size_t)d * 256 + lane * 4) = o;
}

// ---------------- pool + fused MLP ----------------

__global__ void k_pool(const __half* __restrict__ act2h, const int* __restrict__ batch, int N,
                       float* __restrict__ pooled) {
    int g = blockIdx.x;
    int t = threadIdx.x;
    int lo = 0, hi = N;
    while (lo < hi) { int mid = (lo + hi) >> 1; if (batch[mid] < g) lo = mid + 1; else hi = mid; }
    int start = lo;
    lo = start; hi = N;
    while (lo < hi) { int mid = (lo + hi) >> 1; if (batch[mid] < g + 1) lo = mid + 1; else hi = mid; }
    int end = lo;
    float m = -INFINITY;
    for (int n = start; n < end; ++n) m = fmaxf(m, __half2float(act2h[(size_t)n * 256 + t]));
    pooled[g * 256 + t] = m;
}

// whole MLP per GPB graphs in one block: pooled[256] -> relu(512) -> relu(1024) -> 4
__global__ void k_mlp(const float* __restrict__ pooled,
                      const float* __restrict__ Wl1, const float* __restrict__ bl1,
                      const float* __restrict__ Wl2, const float* __restrict__ bl2,
                      const float* __restrict__ Wl3, const float* __restrict__ bl3,
                      float* __restrict__ out, int G) {
    __shared__ float sP[GPB][256];
    __shared__ float sZ1[GPB][512];
    __shared__ float sZ2[GPB][1024];
    __shared__ float sRed[4][GPB][4];
    int t = threadIdx.x;
    int g0 = blockIdx.x * GPB;
#pragma unroll
    for (int g = 0; g < GPB; ++g) sP[g][t] = pooled[(size_t)(g0 + g) * 256 + t];
    __syncthreads();

    // phase 1: [GPB,256] @ [256,512]
    {
        float a00 = 0.f, a01 = 0.f, a10 = 0.f, a11 = 0.f;
#pragma unroll 4
        for (int k = 0; k < 256; ++k) {
            float w0 = Wl1[k * 512 + t];
            float w1 = Wl1[k * 512 + t + 256];
            float p0 = sP[0][k];
            float p1 = sP[1][k];
            a00 += p0 * w0; a01 += p0 * w1;
            a10 += p1 * w0; a11 += p1 * w1;
        }
        float b0 = bl1[t], b1 = bl1[t + 256];
        sZ1[0][t]       = fmaxf(a00 + b0, 0.f);
        sZ1[0][t + 256] = fmaxf(a01 + b1, 0.f);
        sZ1[1][t]       = fmaxf(a10 + b0, 0.f);
        sZ1[1][t + 256] = fmaxf(a11 + b1, 0.f);
    }
    __syncthreads();

    // phase 2: [GPB,512] @ [512,1024]
    {
        float acc[GPB][4];
#pragma unroll
        for (int g = 0; g < GPB; ++g)
#pragma unroll
            for (int c = 0; c < 4; ++c) acc[g][c] = 0.f;
#pragma unroll 4
        for (int k = 0; k < 512; ++k) {
            float w0 = Wl2[k * 1024 + t];
            float w1 = Wl2[k * 1024 + t + 256];
            float w2 = Wl2[k * 1024 + t + 512];
            float w3 = Wl2[k * 1024 + t + 768];
            float z0 = sZ1[0][k];
            float z1 = sZ1[1][k];
            acc[0][0] += z0 * w0; acc[0][1] += z0 * w1; acc[0][2] += z0 * w2; acc[0][3] += z0 * w3;
            acc[1][0] += z1 * w0; acc[1][1] += z1 * w1; acc[1][2] += z1 * w2; acc[1][3] += z1 * w3;
        }
#pragma unroll
        for (int g = 0; g < GPB; ++g)
#pragma unroll
            for (int c = 0; c < 4; ++c)
                sZ2[g][t + c * 256] = fmaxf(acc[g][c] + bl2[t + c * 256], 0.f);
    }
    __syncthreads();

    // phase 3: [GPB,1024] @ [1024,4], split-K over threads
    {
        float pr[GPB][4];
#pragma unroll
        for (int g = 0; g < GPB; ++g)
#pragma unroll
            for (int c = 0; c < 4; ++c) pr[g][c] = 0.f;
#pragma unroll
        for (int kk = 0; kk < 4; ++kk) {
            int k = t + kk * 256;
            float4 w = ((const float4*)Wl3)[k];
            float z0 = sZ2[0][k];
            float z1 = sZ2[1][k];
            pr[0][0] += z0 * w.x; pr[0][1] += z0 * w.y; pr[0][2] += z0 * w.z; pr[0][3] += z0 * w.w;
            pr[1][0] += z1 * w.x; pr[1][1] += z1 * w.y; pr[1][2] += z1 * w.z; pr[1][3] += z1 * w.w;
        }
        int wave = t >> 6, lane = t & 63;
#pragma unroll
        for (int g = 0; g < GPB; ++g)
#pragma unroll
            for (int c = 0; c < 4; ++c) {
                float v = pr[g][c];
#pragma unroll
                for (int off = 32; off >= 1; off >>= 1) v += __shfl_xor(v, off);
                if (lane == 0) sRed[wave][g][c] = v;
            }
        __syncthreads();
        if (t < GPB * 4) {
            int g = t >> 2, c = t & 3;
            float v = sRed[0][g][c] + sRed[1][g][c] + sRed[2][g][c] + sRed[3][g][c];
            out[(size_t)(g0 + g) * 4 + c] = v + bl3[c];
        }
    }
}

extern "C" void kernel_launch(void* const* d_in, const int* in_sizes, int n_in,
                              void* d_out, int out_size, void* d_ws, size_t ws_size,
                              hipStream_t stream) {
    const float* x      = (const float*)d_in[0];
    const int*   ei     = (const int*)d_in[1];
    const int*   batch  = (const int*)d_in[2];
    const float* W1     = (const float*)d_in[3];
    const float* a_src1 = (const float*)d_in[4];
    const float* a_dst1 = (const float*)d_in[5];
    const float* b1     = (const float*)d_in[6];
    const float* W2     = (const float*)d_in[7];
    const float* a_src2 = (const float*)d_in[8];
    const float* a_dst2 = (const float*)d_in[9];
    const float* b2     = (const float*)d_in[10];
    const float* Wl1    = (const float*)d_in[11];
    const float* bl1    = (const float*)d_in[12];
    const float* Wl2    = (const float*)d_in[13];
    const float* bl2    = (const float*)d_in[14];
    const float* Wl3    = (const float*)d_in[15];
    const float* bl3    = (const float*)d_in[16];

    const int N = in_sizes[0] / 27;   // 50000
    const int E = in_sizes[1] / 2;    // 800000
    const int G = out_size / 4;       // 256
    const int EN = E + N;

    const int* srcA = ei;
    const int* dstA = ei + E;

    // ---- workspace layout (ints, fp32, then fp16; all chunks 16B-aligned) ----
    char* wp = (char*)d_ws;
    int* deg    = (int*)wp; wp += (size_t)N * 4;
    int* offs   = (int*)wp; wp += (size_t)N * 4;
    int* cursor = (int*)wp; wp += (size_t)N * 4;
    int* bsum   = (int*)wp; wp += (size_t)SCANB * 4;
    int* csr    = (int*)wp; wp += (size_t)EN * 4;

    float* ssrc1 = (float*)wp; wp += (size_t)N * 4 * 4;
    float* sdst1 = (float*)wp; wp += (size_t)N * 4 * 4;
    float* act1  = (float*)wp; wp += (size_t)N * 64 * 4;
    float* ssrc2 = (float*)wp; wp += (size_t)N * 4;
    float* sdst2 = (float*)wp; wp += (size_t)N * 4;
    float* pooled= (float*)wp; wp += (size_t)G * 256 * 4;

    __half* h1h   = (__half*)wp; wp += (size_t)N * 64 * 2;
    __half* h2h   = (__half*)wp; wp += (size_t)N * 256 * 2;
    __half* act2h = (__half*)wp; wp += (size_t)N * 256 * 2;

    const int nb = (N + SCANB - 1) / SCANB;  // 196 <= 256

    // ---- CSR build (shared by both layers) ----
    hipMemsetAsync(deg, 0, (size_t)N * 4, stream);
    k_hist<<<(EN + 255) / 256, 256, 0, stream>>>(srcA, dstA, E, N, deg);
    k_scan1<<<nb, SCANB, 0, stream>>>(deg, offs, bsum, N);
    k_scan2<<<1, SCANB, 0, stream>>>(bsum, nb);
    k_scan3<<<nb, SCANB, 0, stream>>>(offs, bsum, N);
    hipMemcpyAsync(cursor, offs, (size_t)N * 4, hipMemcpyDeviceToDevice, stream);
    k_scatter<<<(EN + 255) / 256, 256, 0, stream>>>(srcA, dstA, E, N, cursor, csr);

    // ---- layer 1 ----
    k_h1<<<(N + 3) / 4, 256, 0, stream>>>(x, W1, a_src1, a_dst1, h1h, ssrc1, sdst1, N);
    k_gat1<<<(N + 3) / 4, 256, 0, stream>>>(csr, offs, deg, ssrc1, sdst1, h1h, b1, act1, N);

    // ---- layer 2 ----
    k_h2s<<<(N + 7) / 8, 256, 0, stream>>>(act1, W2, a_src2, a_dst2, h2h, ssrc2, sdst2, N);
    k_gat2<<<(N + 3) / 4, 256, 0, stream>>>(csr, offs, deg, ssrc2, sdst2, h2h, b2, act2h, N);

    // ---- pool + fused MLP ----
    k_pool<<<G, 256, 0, stream>>>(act2h, batch, N, pooled);
    k_mlp<<<G / GPB, 256, 0, stream>>>(pooled, Wl1, bl1, Wl2, bl2, Wl3, bl3, (float*)d_out, G);
}

// Round 5
// 378.661 us; speedup vs baseline: 4.8016x; 1.2107x over previous
//
#include <hip/hip_runtime.h>
#include <hip/hip_fp16.h>
#include <math.h>

#define NEG_SLOPE 0.2f
#define SCANB 256

__device__ __forceinline__ float leaky(float x) { return x >= 0.f ? x : NEG_SLOPE * x; }
__device__ __forceinline__ float elu(float x) { return x > 0.f ? x : expm1f(x); }

struct Half4 { __half2 a, b; };

// ---------------- CSR build ----------------

__global__ void k_hist(const int* __restrict__ src, const int* __restrict__ dst, int E, int N,
                       int* __restrict__ deg) {
    int e = blockIdx.x * blockDim.x + threadIdx.x;
    if (e >= E + N) return;
    int d = (e < E) ? dst[e] : e - E;
    atomicAdd(&deg[d], 1);
}

__global__ void k_scan1(const int* __restrict__ in, int* __restrict__ out,
                        int* __restrict__ bsum, int N) {
    __shared__ int sm[SCANB];
    int i = blockIdx.x * SCANB + threadIdx.x;
    int v = (i < N) ? in[i] : 0;
    sm[threadIdx.x] = v;
    __syncthreads();
    for (int off = 1; off < SCANB; off <<= 1) {
        int t = (threadIdx.x >= off) ? sm[threadIdx.x - off] : 0;
        __syncthreads();
        sm[threadIdx.x] += t;
        __syncthreads();
    }
    if (i < N) out[i] = sm[threadIdx.x] - v;  // exclusive
    if (threadIdx.x == SCANB - 1) bsum[blockIdx.x] = sm[SCANB - 1];
}

__global__ void k_scan2(int* __restrict__ bsum, int nb) {
    __shared__ int sm[SCANB];
    int v = (threadIdx.x < nb) ? bsum[threadIdx.x] : 0;
    sm[threadIdx.x] = v;
    __syncthreads();
    for (int off = 1; off < SCANB; off <<= 1) {
        int t = (threadIdx.x >= off) ? sm[threadIdx.x - off] : 0;
        __syncthreads();
        sm[threadIdx.x] += t;
        __syncthreads();
    }
    if (threadIdx.x < nb) bsum[threadIdx.x] = sm[threadIdx.x] - v;
}

__global__ void k_scan3(int* __restrict__ out, const int* __restrict__ bsum, int N) {
    int i = blockIdx.x * SCANB + threadIdx.x;
    if (i < N) out[i] += bsum[blockIdx.x];
}

__global__ void k_scatter(const int* __restrict__ src, const int* __restrict__ dst, int E, int N,
                          int* __restrict__ cursor, int* __restrict__ csr) {
    int e = blockIdx.x * blockDim.x + threadIdx.x;
    if (e >= E + N) return;
    int s, d;
    if (e < E) { s = src[e]; d = dst[e]; } else { s = d = e - E; }
    int pos = atomicAdd(&cursor[d], 1);
    csr[pos] = s;
}

// ---------------- layer 1 ----------------

// h1 = x @ W1  [N,27]@[27,64] (fp16 out), plus per-head scores s_src/s_dst [N,4] (fp32)
__global__ void k_h1(const float* __restrict__ x, const float* __restrict__ W1,
                     const float* __restrict__ a_src, const float* __restrict__ a_dst,
                     __half* __restrict__ h1h, float* __restrict__ ssrc, float* __restrict__ sdst,
                     int N) {
    __shared__ float sW[27 * 64];
    for (int i = threadIdx.x; i < 27 * 64; i += blockDim.x) sW[i] = W1[i];
    __syncthreads();
    int wave = threadIdx.x >> 6;
    int lane = threadIdx.x & 63;
    int n = blockIdx.x * 4 + wave;
    if (n >= N) return;
    const float* xr = x + (size_t)n * 27;
    float acc = 0.f;
#pragma unroll
    for (int k = 0; k < 27; ++k) acc += xr[k] * sW[k * 64 + lane];
    h1h[(size_t)n * 64 + lane] = __float2half(acc);
    int hd = lane >> 4, c = lane & 15;
    float vs = acc * a_src[hd * 16 + c];
    float vd = acc * a_dst[hd * 16 + c];
#pragma unroll
    for (int off = 8; off >= 1; off >>= 1) {
        vs += __shfl_xor(vs, off);
        vd += __shfl_xor(vd, off);
    }
    if (c == 0) {
        ssrc[n * 4 + hd] = vs;
        sdst[n * 4 + hd] = vd;
    }
}

// gather GAT layer 1: wave per dst node; 4 heads x 16 ch; fused softmax + agg + bias + elu
__global__ void k_gat1(const int* __restrict__ csr, const int* __restrict__ offs,
                       const int* __restrict__ deg,
                       const float* __restrict__ ssrc, const float* __restrict__ sdst,
                       const __half* __restrict__ h1h, const float* __restrict__ bias,
                       float* __restrict__ out, int N) {
    int wave = threadIdx.x >> 6, lane = threadIdx.x & 63;
    int d = blockIdx.x * 4 + wave;
    if (d >= N) return;
    int start = offs[d], dg = deg[d];
    float4 sd = *(const float4*)(sdst + (size_t)d * 4);

    float m0 = -INFINITY, m1 = -INFINITY, m2 = -INFINITY, m3 = -INFINITY;
    for (int j = lane; j < dg; j += 64) {
        int s = csr[start + j];
        float4 a = *(const float4*)(ssrc + (size_t)s * 4);
        m0 = fmaxf(m0, leaky(a.x + sd.x));
        m1 = fmaxf(m1, leaky(a.y + sd.y));
        m2 = fmaxf(m2, leaky(a.z + sd.z));
        m3 = fmaxf(m3, leaky(a.w + sd.w));
    }
#pragma unroll
    for (int off = 32; off >= 1; off >>= 1) {
        m0 = fmaxf(m0, __shfl_xor(m0, off));
        m1 = fmaxf(m1, __shfl_xor(m1, off));
        m2 = fmaxf(m2, __shfl_xor(m2, off));
        m3 = fmaxf(m3, __shfl_xor(m3, off));
    }
    float e0 = 0.f, e1 = 0.f, e2 = 0.f, e3 = 0.f;
    for (int j = lane; j < dg; j += 64) {
        int s = csr[start + j];
        float4 a = *(const float4*)(ssrc + (size_t)s * 4);
        e0 += expf(leaky(a.x + sd.x) - m0);
        e1 += expf(leaky(a.y + sd.y) - m1);
        e2 += expf(leaky(a.z + sd.z) - m2);
        e3 += expf(leaky(a.w + sd.w) - m3);
    }
#pragma unroll
    for (int off = 32; off >= 1; off >>= 1) {
        e0 += __shfl_xor(e0, off);
        e1 += __shfl_xor(e1, off);
        e2 += __shfl_xor(e2, off);
        e3 += __shfl_xor(e3, off);
    }
    float i0 = 1.f / (e0 + 1e-16f), i1 = 1.f / (e1 + 1e-16f);
    float i2 = 1.f / (e2 + 1e-16f), i3 = 1.f / (e3 + 1e-16f);

    int hd = lane >> 4;
    int eidx = lane & 15;
    int base = lane & 48;  // 16*hd
    float mh  = hd == 0 ? m0 : hd == 1 ? m1 : hd == 2 ? m2 : m3;
    float ih  = hd == 0 ? i0 : hd == 1 ? i1 : hd == 2 ? i2 : i3;
    float sdh = hd == 0 ? sd.x : hd == 1 ? sd.y : hd == 2 ? sd.z : sd.w;

    float acc = 0.f;
    // chunks of 16 edges; lane (16*hd + e) computes weight of head hd for edge e
    for (int j0 = 0; j0 < dg; j0 += 16) {
        int j = j0 + eidx;
        int se = 0;
        float w = 0.f;
        if (j < dg) {
            se = csr[start + j];
            float a = ssrc[(size_t)se * 4 + hd];
            w = expf(leaky(a + sdh) - mh) * ih;
        }
        int cnt = min(16, dg - j0);
        for (int jj = 0; jj < cnt; jj += 4) {
#pragma unroll
            for (int u = 0; u < 4; ++u) {
                int s2 = __shfl(se, jj + u);            // lanes 0-15 hold edge ids
                float ww = __shfl(w, base + jj + u);    // head-specific weight
                acc += __half2float(h1h[(size_t)s2 * 64 + lane]) * ww;
            }
        }
    }
    out[(size_t)d * 64 + lane] = elu(acc + bias[lane]);
}

// ---------------- layer 2 ----------------

// h2 = act1 @ W2 (fp16 out) fused with layer-2 scores; 8 nodes/block, 256 threads
__global__ void k_h2s(const float* __restrict__ act1, const float* __restrict__ W2,
                      const float* __restrict__ a_src, const float* __restrict__ a_dst,
                      __half* __restrict__ h2h, float* __restrict__ ssrc,
                      float* __restrict__ sdst, int N) {
    __shared__ float sx[8][64];
    __shared__ float sred[8][4][2];
    int n0 = blockIdx.x * 8;
    int t = threadIdx.x;
    for (int i = t; i < 8 * 64; i += 256) {
        int nn = n0 + (i >> 6);
        sx[i >> 6][i & 63] = (nn < N) ? act1[(size_t)nn * 64 + (i & 63)] : 0.f;
    }
    __syncthreads();
    float acc[8];
#pragma unroll
    for (int j = 0; j < 8; ++j) acc[j] = 0.f;
#pragma unroll 4
    for (int k = 0; k < 64; ++k) {
        float w = W2[(size_t)k * 256 + t];
#pragma unroll
        for (int j = 0; j < 8; ++j) acc[j] += sx[j][k] * w;
    }
    float sa = a_src[t], sda = a_dst[t];
    int wave = t >> 6, lane = t & 63;
#pragma unroll
    for (int j = 0; j < 8; ++j) {
        int nn = n0 + j;
        if (nn < N) h2h[(size_t)nn * 256 + t] = __float2half(acc[j]);
        float vs = acc[j] * sa;
        float vd = acc[j] * sda;
#pragma unroll
        for (int off = 32; off >= 1; off >>= 1) {
            vs += __shfl_xor(vs, off);
            vd += __shfl_xor(vd, off);
        }
        if (lane == 0) { sred[j][wave][0] = vs; sred[j][wave][1] = vd; }
    }
    __syncthreads();
    if (t < 16) {
        int j = t >> 1, which = t & 1;
        int nn = n0 + j;
        if (nn < N) {
            float v = sred[j][0][which] + sred[j][1][which] + sred[j][2][which] + sred[j][3][which];
            if (which == 0) ssrc[nn] = v; else sdst[nn] = v;
        }
    }
}

// gather GAT layer 2: wave per dst node; H=1, 256 channels (4 halves per lane); fused bias+elu
__global__ void k_gat2(const int* __restrict__ csr, const int* __restrict__ offs,
                       const int* __restrict__ deg,
                       const float* __restrict__ ssrc, const float* __restrict__ sdst,
                       const __half* __restrict__ h2h, const float* __restrict__ bias,
                       __half* __restrict__ act2h, int N) {
    int wave = threadIdx.x >> 6, lane = threadIdx.x & 63;
    int d = blockIdx.x * 4 + wave;
    if (d >= N) return;
    int start = offs[d], dg = deg[d];
    float sd = sdst[d];

    float m = -INFINITY;
    for (int j = lane; j < dg; j += 64)
        m = fmaxf(m, leaky(ssrc[csr[start + j]] + sd));
#pragma unroll
    for (int off = 32; off >= 1; off >>= 1) m = fmaxf(m, __shfl_xor(m, off));

    float den = 0.f;
    for (int j = lane; j < dg; j += 64)
        den += expf(leaky(ssrc[csr[start + j]] + sd) - m);
#pragma unroll
    for (int off = 32; off >= 1; off >>= 1) den += __shfl_xor(den, off);
    float inv = 1.f / (den + 1e-16f);

    float ax = 0.f, ay = 0.f, az = 0.f, aw = 0.f;
    for (int j0 = 0; j0 < dg; j0 += 64) {
        int j = j0 + lane;
        int se = 0;
        float w = 0.f;
        if (j < dg) {
            se = csr[start + j];
            w = expf(leaky(ssrc[se] + sd) - m) * inv;
        }
        int cnt = min(64, dg - j0);
        for (int jj = 0; jj < cnt; jj += 4) {
#pragma unroll
            for (int u = 0; u < 4; ++u) {
                int s2 = __shfl(se, jj + u);
                float ww = __shfl(w, jj + u);   // lanes past dg carry w=0
                Half4 hv = *(const Half4*)(h2h + (size_t)s2 * 256 + lane * 4);
                float2 f0 = __half22float2(hv.a);
                float2 f1 = __half22float2(hv.b);
                ax += f0.x * ww;
                ay += f0.y * ww;
                az += f1.x * ww;
                aw += f1.y * ww;
            }
        }
    }
    float4 b = *(const float4*)(bias + lane * 4);
    Half4 o;
    o.a = __floats2half2_rn(elu(ax + b.x), elu(ay + b.y));
    o.b = __floats2half2_rn(elu(az + b.z), elu(aw + b.w));
    *(Half4*)(act2h + (size_t)d * 256 + lane * 4) = o;
}

// ---------------- pool + fused MLP ----------------

__global__ void k_pool(const __half* __restrict__ act2h, const int* __restrict__ batch, int N,
                       float* __restrict__ pooled) {
    int g = blockIdx.x;
    int t = threadIdx.x;
    int lo = 0, hi = N;
    while (lo < hi) { int mid = (lo + hi) >> 1; if (batch[mid] < g) lo = mid + 1; else hi = mid; }
    int start = lo;
    lo = start; hi = N;
    while (lo < hi) { int mid = (lo + hi) >> 1; if (batch[mid] < g + 1) lo = mid + 1; else hi = mid; }
    int end = lo;
    float m = -INFINITY;
    for (int n = start; n < end; ++n) m = fmaxf(m, __half2float(act2h[(size_t)n * 256 + t]));
    pooled[g * 256 + t] = m;
}

// whole MLP for ONE graph per 1024-thread block: pooled[256] -> relu(512) -> relu(1024) -> 4
__global__ __launch_bounds__(1024) void k_mlp(const float* __restrict__ pooled,
                      const float* __restrict__ Wl1, const float* __restrict__ bl1,
                      const float* __restrict__ Wl2, const float* __restrict__ bl2,
                      const float* __restrict__ Wl3, const float* __restrict__ bl3,
                      float* __restrict__ out, int G) {
    __shared__ float sP[256];
    __shared__ float sZ1[512];
    __shared__ float sT[1024];
    __shared__ float sZ2[1024];
    int t = threadIdx.x;
    int g = blockIdx.x;
    if (t < 256) sP[t] = pooled[(size_t)g * 256 + t];
    __syncthreads();

    // phase 1: 512 cols, 2 threads/col (K=256 split 2x128)
    {
        int col = t & 511;
        int half = t >> 9;
        const float* W = Wl1 + (size_t)(half * 128) * 512 + col;
        float a = 0.f;
#pragma unroll 8
        for (int k = 0; k < 128; ++k) a += sP[half * 128 + k] * W[(size_t)k * 512];
        sT[t] = a;
    }
    __syncthreads();
    if (t < 512) sZ1[t] = fmaxf(sT[t] + sT[t + 512] + bl1[t], 0.f);
    __syncthreads();

    // phase 2: 1024 cols, 1 thread/col, K=512
    {
        const float* W = Wl2 + t;
        float a = 0.f;
#pragma unroll 8
        for (int k = 0; k < 512; ++k) a += sZ1[k] * W[(size_t)k * 1024];
        sZ2[t] = fmaxf(a + bl2[t], 0.f);
    }
    __syncthreads();

    // phase 3: 4 outputs, K=1024 split across all threads
    {
        float4 w = ((const float4*)Wl3)[t];
        float z = sZ2[t];
        float p0 = z * w.x, p1 = z * w.y, p2 = z * w.z, p3 = z * w.w;
#pragma unroll
        for (int off = 32; off >= 1; off >>= 1) {
            p0 += __shfl_xor(p0, off);
            p1 += __shfl_xor(p1, off);
            p2 += __shfl_xor(p2, off);
            p3 += __shfl_xor(p3, off);
        }
        int wave = t >> 6, lane = t & 63;
        __syncthreads();  // sT reuse
        if (lane == 0) {
            sT[wave * 4 + 0] = p0;
            sT[wave * 4 + 1] = p1;
            sT[wave * 4 + 2] = p2;
            sT[wave * 4 + 3] = p3;
        }
        __syncthreads();
        if (t < 4) {
            float v = bl3[t];
#pragma unroll
            for (int wv = 0; wv < 16; ++wv) v += sT[wv * 4 + t];
            out[(size_t)g * 4 + t] = v;
        }
    }
}

extern "C" void kernel_launch(void* const* d_in, const int* in_sizes, int n_in,
                              void* d_out, int out_size, void* d_ws, size_t ws_size,
                              hipStream_t stream) {
    const float* x      = (const float*)d_in[0];
    const int*   ei     = (const int*)d_in[1];
    const int*   batch  = (const int*)d_in[2];
    const float* W1     = (const float*)d_in[3];
    const float* a_src1 = (const float*)d_in[4];
    const float* a_dst1 = (const float*)d_in[5];
    const float* b1     = (const float*)d_in[6];
    const float* W2     = (const float*)d_in[7];
    const float* a_src2 = (const float*)d_in[8];
    const float* a_dst2 = (const float*)d_in[9];
    const float* b2     = (const float*)d_in[10];
    const float* Wl1    = (const float*)d_in[11];
    const float* bl1    = (const float*)d_in[12];
    const float* Wl2    = (const float*)d_in[13];
    const float* bl2    = (const float*)d_in[14];
    const float* Wl3    = (const float*)d_in[15];
    const float* bl3    = (const float*)d_in[16];

    const int N = in_sizes[0] / 27;   // 50000
    const int E = in_sizes[1] / 2;    // 800000
    const int G = out_size / 4;       // 256
    const int EN = E + N;

    const int* srcA = ei;
    const int* dstA = ei + E;

    // ---- workspace layout (ints, fp32, then fp16; all chunks 16B-aligned) ----
    char* wp = (char*)d_ws;
    int* deg    = (int*)wp; wp += (size_t)N * 4;
    int* offs   = (int*)wp; wp += (size_t)N * 4;
    int* cursor = (int*)wp; wp += (size_t)N * 4;
    int* bsum   = (int*)wp; wp += (size_t)SCANB * 4;
    int* csr    = (int*)wp; wp += (size_t)EN * 4;

    float* ssrc1 = (float*)wp; wp += (size_t)N * 4 * 4;
    float* sdst1 = (float*)wp; wp += (size_t)N * 4 * 4;
    float* act1  = (float*)wp; wp += (size_t)N * 64 * 4;
    float* ssrc2 = (float*)wp; wp += (size_t)N * 4;
    float* sdst2 = (float*)wp; wp += (size_t)N * 4;
    float* pooled= (float*)wp; wp += (size_t)G * 256 * 4;

    __half* h1h   = (__half*)wp; wp += (size_t)N * 64 * 2;
    __half* h2h   = (__half*)wp; wp += (size_t)N * 256 * 2;
    __half* act2h = (__half*)wp; wp += (size_t)N * 256 * 2;

    const int nb = (N + SCANB - 1) / SCANB;  // 196 <= 256

    // ---- CSR build (shared by both layers) ----
    hipMemsetAsync(deg, 0, (size_t)N * 4, stream);
    k_hist<<<(EN + 255) / 256, 256, 0, stream>>>(srcA, dstA, E, N, deg);
    k_scan1<<<nb, SCANB, 0, stream>>>(deg, offs, bsum, N);
    k_scan2<<<1, SCANB, 0, stream>>>(bsum, nb);
    k_scan3<<<nb, SCANB, 0, stream>>>(offs, bsum, N);
    hipMemcpyAsync(cursor, offs, (size_t)N * 4, hipMemcpyDeviceToDevice, stream);
    k_scatter<<<(EN + 255) / 256, 256, 0, stream>>>(srcA, dstA, E, N, cursor, csr);

    // ---- layer 1 ----
    k_h1<<<(N + 3) / 4, 256, 0, stream>>>(x, W1, a_src1, a_dst1, h1h, ssrc1, sdst1, N);
    k_gat1<<<(N + 3) / 4, 256, 0, stream>>>(csr, offs, deg, ssrc1, sdst1, h1h, b1, act1, N);

    // ---- layer 2 ----
    k_h2s<<<(N + 7) / 8, 256, 0, stream>>>(act1, W2, a_src2, a_dst2, h2h, ssrc2, sdst2, N);
    k_gat2<<<(N + 3) / 4, 256, 0, stream>>>(csr, offs, deg, ssrc2, sdst2, h2h, b2, act2h, N);

    // ---- pool + fused MLP ----
    k_pool<<<G, 256, 0, stream>>>(act2h, batch, N, pooled);
    k_mlp<<<G, 1024, 0, stream>>>(pooled, Wl1, bl1, Wl2, bl2, Wl3, bl3, (float*)d_out, G);
}

// Round 6
// 347.054 us; speedup vs baseline: 5.2389x; 1.0911x over previous
//
#include <hip/hip_runtime.h>
#include <hip/hip_fp16.h>
#include <math.h>

#define NEG_SLOPE 0.2f
#define SCANB 256

__device__ __forceinline__ float leaky(float x) { return x >= 0.f ? x : NEG_SLOPE * x; }
__device__ __forceinline__ float elu(float x) { return x > 0.f ? x : expm1f(x); }

struct Half4 { __half2 a, b; };

typedef _Float16 half8 __attribute__((ext_vector_type(8)));
typedef float floatx4 __attribute__((ext_vector_type(4)));

// ---------------- CSR build ----------------

__global__ void k_hist(const int* __restrict__ src, const int* __restrict__ dst, int E, int N,
                       int* __restrict__ deg) {
    int e = blockIdx.x * blockDim.x + threadIdx.x;
    if (e >= E + N) return;
    int d = (e < E) ? dst[e] : e - E;
    atomicAdd(&deg[d], 1);
}

__global__ void k_scan1(const int* __restrict__ in, int* __restrict__ out,
                        int* __restrict__ bsum, int N) {
    __shared__ int sm[SCANB];
    int i = blockIdx.x * SCANB + threadIdx.x;
    int v = (i < N) ? in[i] : 0;
    sm[threadIdx.x] = v;
    __syncthreads();
    for (int off = 1; off < SCANB; off <<= 1) {
        int t = (threadIdx.x >= off) ? sm[threadIdx.x - off] : 0;
        __syncthreads();
        sm[threadIdx.x] += t;
        __syncthreads();
    }
    if (i < N) out[i] = sm[threadIdx.x] - v;  // exclusive
    if (threadIdx.x == SCANB - 1) bsum[blockIdx.x] = sm[SCANB - 1];
}

__global__ void k_scan2(int* __restrict__ bsum, int nb) {
    __shared__ int sm[SCANB];
    int v = (threadIdx.x < nb) ? bsum[threadIdx.x] : 0;
    sm[threadIdx.x] = v;
    __syncthreads();
    for (int off = 1; off < SCANB; off <<= 1) {
        int t = (threadIdx.x >= off) ? sm[threadIdx.x - off] : 0;
        __syncthreads();
        sm[threadIdx.x] += t;
        __syncthreads();
    }
    if (threadIdx.x < nb) bsum[threadIdx.x] = sm[threadIdx.x] - v;
}

__global__ void k_scan3(int* __restrict__ out, const int* __restrict__ bsum, int N) {
    int i = blockIdx.x * SCANB + threadIdx.x;
    if (i < N) out[i] += bsum[blockIdx.x];
}

__global__ void k_scatter(const int* __restrict__ src, const int* __restrict__ dst, int E, int N,
                          int* __restrict__ cursor, int* __restrict__ csr) {
    int e = blockIdx.x * blockDim.x + threadIdx.x;
    if (e >= E + N) return;
    int s, d;
    if (e < E) { s = src[e]; d = dst[e]; } else { s = d = e - E; }
    int pos = atomicAdd(&cursor[d], 1);
    csr[pos] = s;
}

// ---------------- weight prep ----------------

__global__ void k_f2h(const float* __restrict__ src, __half* __restrict__ dst, int n) {
    int i = blockIdx.x * blockDim.x + threadIdx.x;
    if (i < n) dst[i] = __float2half(src[i]);
}

// W2t[c][k] = W2[k][c] as fp16; W2 is [64][256]
__global__ void k_w2t(const float* __restrict__ W2, __half* __restrict__ W2t) {
    int i = blockIdx.x * blockDim.x + threadIdx.x;  // 16384
    int k = i >> 8, c = i & 255;
    W2t[c * 64 + k] = __float2half(W2[i]);
}

// ---------------- layer 1 ----------------

// h1 = x @ W1  [N,27]@[27,64] (fp16 out), plus per-head scores s_src/s_dst [N,4] (fp32)
__global__ void k_h1(const float* __restrict__ x, const float* __restrict__ W1,
                     const float* __restrict__ a_src, const float* __restrict__ a_dst,
                     __half* __restrict__ h1h, float* __restrict__ ssrc, float* __restrict__ sdst,
                     int N) {
    __shared__ float sW[27 * 64];
    for (int i = threadIdx.x; i < 27 * 64; i += blockDim.x) sW[i] = W1[i];
    __syncthreads();
    int wave = threadIdx.x >> 6;
    int lane = threadIdx.x & 63;
    int n = blockIdx.x * 4 + wave;
    if (n >= N) return;
    const float* xr = x + (size_t)n * 27;
    float acc = 0.f;
#pragma unroll
    for (int k = 0; k < 27; ++k) acc += xr[k] * sW[k * 64 + lane];
    h1h[(size_t)n * 64 + lane] = __float2half(acc);
    int hd = lane >> 4, c = lane & 15;
    float vs = acc * a_src[hd * 16 + c];
    float vd = acc * a_dst[hd * 16 + c];
#pragma unroll
    for (int off = 8; off >= 1; off >>= 1) {
        vs += __shfl_xor(vs, off);
        vd += __shfl_xor(vd, off);
    }
    if (c == 0) {
        ssrc[n * 4 + hd] = vs;
        sdst[n * 4 + hd] = vd;
    }
}

// gather GAT layer 1: wave per dst node; 4 heads x 16 ch; fused softmax + agg + bias + elu
__global__ void k_gat1(const int* __restrict__ csr, const int* __restrict__ offs,
                       const int* __restrict__ deg,
                       const float* __restrict__ ssrc, const float* __restrict__ sdst,
                       const __half* __restrict__ h1h, const float* __restrict__ bias,
                       __half* __restrict__ out, int N) {
    int wave = threadIdx.x >> 6, lane = threadIdx.x & 63;
    int d = blockIdx.x * 4 + wave;
    if (d >= N) return;
    int start = offs[d], dg = deg[d];
    float4 sd = *(const float4*)(sdst + (size_t)d * 4);

    float m0 = -INFINITY, m1 = -INFINITY, m2 = -INFINITY, m3 = -INFINITY;
    for (int j = lane; j < dg; j += 64) {
        int s = csr[start + j];
        float4 a = *(const float4*)(ssrc + (size_t)s * 4);
        m0 = fmaxf(m0, leaky(a.x + sd.x));
        m1 = fmaxf(m1, leaky(a.y + sd.y));
        m2 = fmaxf(m2, leaky(a.z + sd.z));
        m3 = fmaxf(m3, leaky(a.w + sd.w));
    }
#pragma unroll
    for (int off = 32; off >= 1; off >>= 1) {
        m0 = fmaxf(m0, __shfl_xor(m0, off));
        m1 = fmaxf(m1, __shfl_xor(m1, off));
        m2 = fmaxf(m2, __shfl_xor(m2, off));
        m3 = fmaxf(m3, __shfl_xor(m3, off));
    }
    float e0 = 0.f, e1 = 0.f, e2 = 0.f, e3 = 0.f;
    for (int j = lane; j < dg; j += 64) {
        int s = csr[start + j];
        float4 a = *(const float4*)(ssrc + (size_t)s * 4);
        e0 += expf(leaky(a.x + sd.x) - m0);
        e1 += expf(leaky(a.y + sd.y) - m1);
        e2 += expf(leaky(a.z + sd.z) - m2);
        e3 += expf(leaky(a.w + sd.w) - m3);
    }
#pragma unroll
    for (int off = 32; off >= 1; off >>= 1) {
        e0 += __shfl_xor(e0, off);
        e1 += __shfl_xor(e1, off);
        e2 += __shfl_xor(e2, off);
        e3 += __shfl_xor(e3, off);
    }
    float i0 = 1.f / (e0 + 1e-16f), i1 = 1.f / (e1 + 1e-16f);
    float i2 = 1.f / (e2 + 1e-16f), i3 = 1.f / (e3 + 1e-16f);

    int hd = lane >> 4;
    int eidx = lane & 15;
    int base = lane & 48;  // 16*hd
    float mh  = hd == 0 ? m0 : hd == 1 ? m1 : hd == 2 ? m2 : m3;
    float ih  = hd == 0 ? i0 : hd == 1 ? i1 : hd == 2 ? i2 : i3;
    float sdh = hd == 0 ? sd.x : hd == 1 ? sd.y : hd == 2 ? sd.z : sd.w;

    float acc = 0.f;
    for (int j0 = 0; j0 < dg; j0 += 16) {
        int j = j0 + eidx;
        int se = 0;
        float w = 0.f;
        if (j < dg) {
            se = csr[start + j];
            float a = ssrc[(size_t)se * 4 + hd];
            w = expf(leaky(a + sdh) - mh) * ih;
        }
        int cnt = min(16, dg - j0);
        for (int jj = 0; jj < cnt; jj += 4) {
#pragma unroll
            for (int u = 0; u < 4; ++u) {
                int s2 = __shfl(se, jj + u);            // lanes 0-15 hold edge ids
                float ww = __shfl(w, base + jj + u);    // head-specific weight
                acc += __half2float(h1h[(size_t)s2 * 64 + lane]) * ww;
            }
        }
    }
    out[(size_t)d * 64 + lane] = __float2half(elu(acc + bias[lane]));
}

// ---------------- layer 2 ----------------

// h2 = act1h @ W2 via MFMA (fp16 in, fp32 acc, fp16 out) + fused layer-2 scores.
// block: 256 threads = 4 waves; 16 nodes x 256 cols; wave wv covers cols [64wv, 64wv+64)
__global__ void k_h2m(const __half* __restrict__ act1h, const __half* __restrict__ W2t,
                      const float* __restrict__ a_src, const float* __restrict__ a_dst,
                      __half* __restrict__ h2h, float* __restrict__ ssrc,
                      float* __restrict__ sdst, int N) {
    __shared__ float sred[2][4][16];  // [src/dst][wave][node]
    int t = threadIdx.x;
    int wv = t >> 6, lane = t & 63;
    int lr = lane & 15, lg = lane >> 4;
    int n0 = blockIdx.x * 16;

    half8 a0 = {0, 0, 0, 0, 0, 0, 0, 0};
    half8 a1 = {0, 0, 0, 0, 0, 0, 0, 0};
    int nodeA = n0 + lr;
    if (nodeA < N) {
        a0 = *(const half8*)(act1h + (size_t)nodeA * 64 + lg * 8);
        a1 = *(const half8*)(act1h + (size_t)nodeA * 64 + 32 + lg * 8);
    }

    float ps[4] = {0.f, 0.f, 0.f, 0.f};
    float pd[4] = {0.f, 0.f, 0.f, 0.f};
#pragma unroll
    for (int c = 0; c < 4; ++c) {
        int col = wv * 64 + c * 16 + lr;
        half8 b0 = *(const half8*)(W2t + (size_t)col * 64 + lg * 8);
        half8 b1 = *(const half8*)(W2t + (size_t)col * 64 + 32 + lg * 8);
        floatx4 acc = {0.f, 0.f, 0.f, 0.f};
        acc = __builtin_amdgcn_mfma_f32_16x16x32_f16(a0, b0, acc, 0, 0, 0);
        acc = __builtin_amdgcn_mfma_f32_16x16x32_f16(a1, b1, acc, 0, 0, 0);
        float as = a_src[col], ad = a_dst[col];
#pragma unroll
        for (int r = 0; r < 4; ++r) {
            int node = n0 + lg * 4 + r;
            if (node < N) h2h[(size_t)node * 256 + col] = __float2half(acc[r]);
            ps[r] += acc[r] * as;
            pd[r] += acc[r] * ad;
        }
    }
#pragma unroll
    for (int r = 0; r < 4; ++r) {
#pragma unroll
        for (int off = 8; off >= 1; off >>= 1) {
            ps[r] += __shfl_xor(ps[r], off);
            pd[r] += __shfl_xor(pd[r], off);
        }
        if (lr == 0) {
            sred[0][wv][lg * 4 + r] = ps[r];
            sred[1][wv][lg * 4 + r] = pd[r];
        }
    }
    __syncthreads();
    if (t < 32) {
        int which = t >> 4, node = t & 15;
        int nn = n0 + node;
        if (nn < N) {
            float v = sred[which][0][node] + sred[which][1][node] +
                      sred[which][2][node] + sred[which][3][node];
            if (which == 0) ssrc[nn] = v; else sdst[nn] = v;
        }
    }
}

// gather GAT layer 2: wave per dst node; H=1, 256 channels (4 halves per lane); fused bias+elu
__global__ void k_gat2(const int* __restrict__ csr, const int* __restrict__ offs,
                       const int* __restrict__ deg,
                       const float* __restrict__ ssrc, const float* __restrict__ sdst,
                       const __half* __restrict__ h2h, const float* __restrict__ bias,
                       __half* __restrict__ act2h, int N) {
    int wave = threadIdx.x >> 6, lane = threadIdx.x & 63;
    int d = blockIdx.x * 4 + wave;
    if (d >= N) return;
    int start = offs[d], dg = deg[d];
    float sd = sdst[d];

    float m = -INFINITY;
    for (int j = lane; j < dg; j += 64)
        m = fmaxf(m, leaky(ssrc[csr[start + j]] + sd));
#pragma unroll
    for (int off = 32; off >= 1; off >>= 1) m = fmaxf(m, __shfl_xor(m, off));

    float den = 0.f;
    for (int j = lane; j < dg; j += 64)
        den += expf(leaky(ssrc[csr[start + j]] + sd) - m);
#pragma unroll
    for (int off = 32; off >= 1; off >>= 1) den += __shfl_xor(den, off);
    float inv = 1.f / (den + 1e-16f);

    float ax = 0.f, ay = 0.f, az = 0.f, aw = 0.f;
    for (int j0 = 0; j0 < dg; j0 += 64) {
        int j = j0 + lane;
        int se = 0;
        float w = 0.f;
        if (j < dg) {
            se = csr[start + j];
            w = expf(leaky(ssrc[se] + sd) - m) * inv;
        }
        int cnt = min(64, dg - j0);
        for (int jj = 0; jj < cnt; jj += 4) {
#pragma unroll
            for (int u = 0; u < 4; ++u) {
                int s2 = __shfl(se, jj + u);
                float ww = __shfl(w, jj + u);   // lanes past dg carry w=0
                Half4 hv = *(const Half4*)(h2h + (size_t)s2 * 256 + lane * 4);
                float2 f0 = __half22float2(hv.a);
                float2 f1 = __half22float2(hv.b);
                ax += f0.x * ww;
                ay += f0.y * ww;
                az += f1.x * ww;
                aw += f1.y * ww;
            }
        }
    }
    float4 b = *(const float4*)(bias + lane * 4);
    Half4 o;
    o.a = __floats2half2_rn(elu(ax + b.x), elu(ay + b.y));
    o.b = __floats2half2_rn(elu(az + b.z), elu(aw + b.w));
    *(Half4*)(act2h + (size_t)d * 256 + lane * 4) = o;
}

// ---------------- pool + fused MLP ----------------

__global__ void k_pool(const __half* __restrict__ act2h, const int* __restrict__ batch, int N,
                       float* __restrict__ pooled) {
    int g = blockIdx.x;
    int t = threadIdx.x;
    int lo = 0, hi = N;
    while (lo < hi) { int mid = (lo + hi) >> 1; if (batch[mid] < g) lo = mid + 1; else hi = mid; }
    int start = lo;
    lo = start; hi = N;
    while (lo < hi) { int mid = (lo + hi) >> 1; if (batch[mid] < g + 1) lo = mid + 1; else hi = mid; }
    int end = lo;
    float m = -INFINITY;
    for (int n = start; n < end; ++n) m = fmaxf(m, __half2float(act2h[(size_t)n * 256 + t]));
    pooled[g * 256 + t] = m;
}

// whole MLP for ONE graph per 1024-thread block; Wl1/Wl2 in fp16
__global__ __launch_bounds__(1024) void k_mlp(const float* __restrict__ pooled,
                      const __half* __restrict__ Wl1h, const float* __restrict__ bl1,
                      const __half* __restrict__ Wl2h, const float* __restrict__ bl2,
                      const float* __restrict__ Wl3, const float* __restrict__ bl3,
                      float* __restrict__ out, int G) {
    __shared__ float sP[256];
    __shared__ float sZ1[512];
    __shared__ float sT[1024];
    __shared__ float sZ2[1024];
    int t = threadIdx.x;
    int g = blockIdx.x;
    if (t < 256) sP[t] = pooled[(size_t)g * 256 + t];
    __syncthreads();

    // phase 1: 512 cols, 2 threads/col (K=256 split 2x128)
    {
        int col = t & 511;
        int half = t >> 9;
        const __half* W = Wl1h + (size_t)(half * 128) * 512 + col;
        float a = 0.f;
#pragma unroll 8
        for (int k = 0; k < 128; ++k) a += sP[half * 128 + k] * __half2float(W[(size_t)k * 512]);
        sT[t] = a;
    }
    __syncthreads();
    if (t < 512) sZ1[t] = fmaxf(sT[t] + sT[t + 512] + bl1[t], 0.f);
    __syncthreads();

    // phase 2: 1024 cols, 1 thread/col, K=512
    {
        const __half* W = Wl2h + t;
        float a = 0.f;
#pragma unroll 8
        for (int k = 0; k < 512; ++k) a += sZ1[k] * __half2float(W[(size_t)k * 1024]);
        sZ2[t] = fmaxf(a + bl2[t], 0.f);
    }
    __syncthreads();

    // phase 3: 4 outputs, K=1024 split across all threads
    {
        float4 w = ((const float4*)Wl3)[t];
        float z = sZ2[t];
        float p0 = z * w.x, p1 = z * w.y, p2 = z * w.z, p3 = z * w.w;
#pragma unroll
        for (int off = 32; off >= 1; off >>= 1) {
            p0 += __shfl_xor(p0, off);
            p1 += __shfl_xor(p1, off);
            p2 += __shfl_xor(p2, off);
            p3 += __shfl_xor(p3, off);
        }
        int wave = t >> 6, lane = t & 63;
        __syncthreads();  // sT reuse
        if (lane == 0) {
            sT[wave * 4 + 0] = p0;
            sT[wave * 4 + 1] = p1;
            sT[wave * 4 + 2] = p2;
            sT[wave * 4 + 3] = p3;
        }
        __syncthreads();
        if (t < 4) {
            float v = bl3[t];
#pragma unroll
            for (int wv = 0; wv < 16; ++wv) v += sT[wv * 4 + t];
            out[(size_t)g * 4 + t] = v;
        }
    }
}

extern "C" void kernel_launch(void* const* d_in, const int* in_sizes, int n_in,
                              void* d_out, int out_size, void* d_ws, size_t ws_size,
                              hipStream_t stream) {
    const float* x      = (const float*)d_in[0];
    const int*   ei     = (const int*)d_in[1];
    const int*   batch  = (const int*)d_in[2];
    const float* W1     = (const float*)d_in[3];
    const float* a_src1 = (const float*)d_in[4];
    const float* a_dst1 = (const float*)d_in[5];
    const float* b1     = (const float*)d_in[6];
    const float* W2     = (const float*)d_in[7];
    const float* a_src2 = (const float*)d_in[8];
    const float* a_dst2 = (const float*)d_in[9];
    const float* b2     = (const float*)d_in[10];
    const float* Wl1    = (const float*)d_in[11];
    const float* bl1    = (const float*)d_in[12];
    const float* Wl2    = (const float*)d_in[13];
    const float* bl2    = (const float*)d_in[14];
    const float* Wl3    = (const float*)d_in[15];
    const float* bl3    = (const float*)d_in[16];

    const int N = in_sizes[0] / 27;   // 50000
    const int E = in_sizes[1] / 2;    // 800000
    const int G = out_size / 4;       // 256
    const int EN = E + N;

    const int* srcA = ei;
    const int* dstA = ei + E;

    // ---- workspace layout (ints, fp32, then fp16; all chunks 16B-aligned) ----
    char* wp = (char*)d_ws;
    int* deg    = (int*)wp; wp += (size_t)N * 4;
    int* offs   = (int*)wp; wp += (size_t)N * 4;
    int* cursor = (int*)wp; wp += (size_t)N * 4;
    int* bsum   = (int*)wp; wp += (size_t)SCANB * 4;
    int* csr    = (int*)wp; wp += (size_t)EN * 4;

    float* ssrc1 = (float*)wp; wp += (size_t)N * 4 * 4;
    float* sdst1 = (float*)wp; wp += (size_t)N * 4 * 4;
    float* ssrc2 = (float*)wp; wp += (size_t)N * 4;
    float* sdst2 = (float*)wp; wp += (size_t)N * 4;
    float* pooled= (float*)wp; wp += (size_t)G * 256 * 4;

    __half* h1h   = (__half*)wp; wp += (size_t)N * 64 * 2;
    __half* act1h = (__half*)wp; wp += (size_t)N * 64 * 2;
    __half* h2h   = (__half*)wp; wp += (size_t)N * 256 * 2;
    __half* act2h = (__half*)wp; wp += (size_t)N * 256 * 2;
    __half* W2t   = (__half*)wp; wp += (size_t)64 * 256 * 2;
    __half* Wl1h  = (__half*)wp; wp += (size_t)256 * 512 * 2;
    __half* Wl2h  = (__half*)wp; wp += (size_t)512 * 1024 * 2;

    const int nb = (N + SCANB - 1) / SCANB;  // 196 <= 256

    // ---- weight prep ----
    k_w2t<<<64, 256, 0, stream>>>(W2, W2t);
    k_f2h<<<(256 * 512 + 255) / 256, 256, 0, stream>>>(Wl1, Wl1h, 256 * 512);
    k_f2h<<<(512 * 1024 + 255) / 256, 256, 0, stream>>>(Wl2, Wl2h, 512 * 1024);

    // ---- CSR build (shared by both layers) ----
    hipMemsetAsync(deg, 0, (size_t)N * 4, stream);
    k_hist<<<(EN + 255) / 256, 256, 0, stream>>>(srcA, dstA, E, N, deg);
    k_scan1<<<nb, SCANB, 0, stream>>>(deg, offs, bsum, N);
    k_scan2<<<1, SCANB, 0, stream>>>(bsum, nb);
    k_scan3<<<nb, SCANB, 0, stream>>>(offs, bsum, N);
    hipMemcpyAsync(cursor, offs, (size_t)N * 4, hipMemcpyDeviceToDevice, stream);
    k_scatter<<<(EN + 255) / 256, 256, 0, stream>>>(srcA, dstA, E, N, cursor, csr);

    // ---- layer 1 ----
    k_h1<<<(N + 3) / 4, 256, 0, stream>>>(x, W1, a_src1, a_dst1, h1h, ssrc1, sdst1, N);
    k_gat1<<<(N + 3) / 4, 256, 0, stream>>>(csr, offs, deg, ssrc1, sdst1, h1h, b1, act1h, N);

    // ---- layer 2 ----
    k_h2m<<<(N + 15) / 16, 256, 0, stream>>>(act1h, W2t, a_src2, a_dst2, h2h, ssrc2, sdst2, N);
    k_gat2<<<(N + 3) / 4, 256, 0, stream>>>(csr, offs, deg, ssrc2, sdst2, h2h, b2, act2h, N);

    // ---- pool + fused MLP ----
    k_pool<<<G, 256, 0, stream>>>(act2h, batch, N, pooled);
    k_mlp<<<G, 1024, 0, stream>>>(pooled, Wl1h, bl1, Wl2h, bl2, Wl3, bl3, (float*)d_out, G);
}

// Round 7
// 337.358 us; speedup vs baseline: 5.3894x; 1.0287x over previous
//
#include <hip/hip_runtime.h>
#include <hip/hip_fp16.h>
#include <math.h>

#define NEG_SLOPE 0.2f
#define SCANB 256

__device__ __forceinline__ float leaky(float x) { return x >= 0.f ? x : NEG_SLOPE * x; }
__device__ __forceinline__ float elu(float x) { return x > 0.f ? x : expm1f(x); }

struct Half4 { __half2 a, b; };

typedef _Float16 half8 __attribute__((ext_vector_type(8)));
typedef float floatx4 __attribute__((ext_vector_type(4)));

// ---------------- CSR build ----------------

__global__ void k_hist(const int* __restrict__ src, const int* __restrict__ dst, int E, int N,
                       int* __restrict__ deg) {
    int e = blockIdx.x * blockDim.x + threadIdx.x;
    if (e >= E + N) return;
    int d = (e < E) ? dst[e] : e - E;
    atomicAdd(&deg[d], 1);
}

__global__ void k_scan1(const int* __restrict__ in, int* __restrict__ out,
                        int* __restrict__ bsum, int N) {
    __shared__ int sm[SCANB];
    int i = blockIdx.x * SCANB + threadIdx.x;
    int v = (i < N) ? in[i] : 0;
    sm[threadIdx.x] = v;
    __syncthreads();
    for (int off = 1; off < SCANB; off <<= 1) {
        int t = (threadIdx.x >= off) ? sm[threadIdx.x - off] : 0;
        __syncthreads();
        sm[threadIdx.x] += t;
        __syncthreads();
    }
    if (i < N) out[i] = sm[threadIdx.x] - v;  // exclusive
    if (threadIdx.x == SCANB - 1) bsum[blockIdx.x] = sm[SCANB - 1];
}

__global__ void k_scan2(int* __restrict__ bsum, int nb) {
    __shared__ int sm[SCANB];
    int v = (threadIdx.x < nb) ? bsum[threadIdx.x] : 0;
    sm[threadIdx.x] = v;
    __syncthreads();
    for (int off = 1; off < SCANB; off <<= 1) {
        int t = (threadIdx.x >= off) ? sm[threadIdx.x - off] : 0;
        __syncthreads();
        sm[threadIdx.x] += t;
        __syncthreads();
    }
    if (threadIdx.x < nb) bsum[threadIdx.x] = sm[threadIdx.x] - v;
}

__global__ void k_scan3(int* __restrict__ out, const int* __restrict__ bsum, int N) {
    int i = blockIdx.x * SCANB + threadIdx.x;
    if (i < N) out[i] += bsum[blockIdx.x];
}

__global__ void k_scatter(const int* __restrict__ src, const int* __restrict__ dst, int E, int N,
                          int* __restrict__ cursor, int* __restrict__ csr) {
    int e = blockIdx.x * blockDim.x + threadIdx.x;
    if (e >= E + N) return;
    int s, d;
    if (e < E) { s = src[e]; d = dst[e]; } else { s = d = e - E; }
    int pos = atomicAdd(&cursor[d], 1);
    csr[pos] = s;
}

// ---------------- weight prep: Wt[n][k] = (fp16) W[k][n] ----------------

__global__ void k_t(const float* __restrict__ W, __half* __restrict__ Wt, int K, int N) {
    int i = blockIdx.x * blockDim.x + threadIdx.x;
    if (i >= K * N) return;
    int k = i / N, n = i % N;
    Wt[(size_t)n * K + k] = __float2half(W[i]);
}

// ---------------- layer 1 ----------------

// h1 = x @ W1  [N,27]@[27,64] (fp16 out), plus per-head scores s_src/s_dst [N,4] (fp32)
__global__ void k_h1(const float* __restrict__ x, const float* __restrict__ W1,
                     const float* __restrict__ a_src, const float* __restrict__ a_dst,
                     __half* __restrict__ h1h, float* __restrict__ ssrc, float* __restrict__ sdst,
                     int N) {
    __shared__ float sW[27 * 64];
    for (int i = threadIdx.x; i < 27 * 64; i += blockDim.x) sW[i] = W1[i];
    __syncthreads();
    int wave = threadIdx.x >> 6;
    int lane = threadIdx.x & 63;
    int n = blockIdx.x * 4 + wave;
    if (n >= N) return;
    const float* xr = x + (size_t)n * 27;
    float acc = 0.f;
#pragma unroll
    for (int k = 0; k < 27; ++k) acc += xr[k] * sW[k * 64 + lane];
    h1h[(size_t)n * 64 + lane] = __float2half(acc);
    int hd = lane >> 4, c = lane & 15;
    float vs = acc * a_src[hd * 16 + c];
    float vd = acc * a_dst[hd * 16 + c];
#pragma unroll
    for (int off = 8; off >= 1; off >>= 1) {
        vs += __shfl_xor(vs, off);
        vd += __shfl_xor(vd, off);
    }
    if (c == 0) {
        ssrc[n * 4 + hd] = vs;
        sdst[n * 4 + hd] = vd;
    }
}

// gather GAT layer 1: wave per dst node; 4 heads x 16 ch; fused softmax + agg + bias + elu
__global__ void k_gat1(const int* __restrict__ csr, const int* __restrict__ offs,
                       const int* __restrict__ deg,
                       const float* __restrict__ ssrc, const float* __restrict__ sdst,
                       const __half* __restrict__ h1h, const float* __restrict__ bias,
                       __half* __restrict__ out, int N) {
    int wave = threadIdx.x >> 6, lane = threadIdx.x & 63;
    int d = blockIdx.x * 4 + wave;
    if (d >= N) return;
    int start = offs[d], dg = deg[d];
    float4 sd = *(const float4*)(sdst + (size_t)d * 4);

    float m0 = -INFINITY, m1 = -INFINITY, m2 = -INFINITY, m3 = -INFINITY;
    for (int j = lane; j < dg; j += 64) {
        int s = csr[start + j];
        float4 a = *(const float4*)(ssrc + (size_t)s * 4);
        m0 = fmaxf(m0, leaky(a.x + sd.x));
        m1 = fmaxf(m1, leaky(a.y + sd.y));
        m2 = fmaxf(m2, leaky(a.z + sd.z));
        m3 = fmaxf(m3, leaky(a.w + sd.w));
    }
#pragma unroll
    for (int off = 32; off >= 1; off >>= 1) {
        m0 = fmaxf(m0, __shfl_xor(m0, off));
        m1 = fmaxf(m1, __shfl_xor(m1, off));
        m2 = fmaxf(m2, __shfl_xor(m2, off));
        m3 = fmaxf(m3, __shfl_xor(m3, off));
    }
    float e0 = 0.f, e1 = 0.f, e2 = 0.f, e3 = 0.f;
    for (int j = lane; j < dg; j += 64) {
        int s = csr[start + j];
        float4 a = *(const float4*)(ssrc + (size_t)s * 4);
        e0 += expf(leaky(a.x + sd.x) - m0);
        e1 += expf(leaky(a.y + sd.y) - m1);
        e2 += expf(leaky(a.z + sd.z) - m2);
        e3 += expf(leaky(a.w + sd.w) - m3);
    }
#pragma unroll
    for (int off = 32; off >= 1; off >>= 1) {
        e0 += __shfl_xor(e0, off);
        e1 += __shfl_xor(e1, off);
        e2 += __shfl_xor(e2, off);
        e3 += __shfl_xor(e3, off);
    }
    float i0 = 1.f / (e0 + 1e-16f), i1 = 1.f / (e1 + 1e-16f);
    float i2 = 1.f / (e2 + 1e-16f), i3 = 1.f / (e3 + 1e-16f);

    int hd = lane >> 4;
    int eidx = lane & 15;
    int base = lane & 48;  // 16*hd
    float mh  = hd == 0 ? m0 : hd == 1 ? m1 : hd == 2 ? m2 : m3;
    float ih  = hd == 0 ? i0 : hd == 1 ? i1 : hd == 2 ? i2 : i3;
    float sdh = hd == 0 ? sd.x : hd == 1 ? sd.y : hd == 2 ? sd.z : sd.w;

    float acc = 0.f;
    for (int j0 = 0; j0 < dg; j0 += 16) {
        int j = j0 + eidx;
        int se = 0;
        float w = 0.f;
        if (j < dg) {
            se = csr[start + j];
            float a = ssrc[(size_t)se * 4 + hd];
            w = expf(leaky(a + sdh) - mh) * ih;
        }
        int cnt = min(16, dg - j0);
        int cnt8 = (cnt + 7) & ~7;       // pad; padded lanes carry w=0, se=0
        for (int jj = 0; jj < cnt8; jj += 8) {
#pragma unroll
            for (int u = 0; u < 8; ++u) {
                int s2 = __shfl(se, jj + u);            // lanes 0-15 hold edge ids
                float ww = __shfl(w, base + jj + u);    // head-specific weight
                acc += __half2float(h1h[(size_t)s2 * 64 + lane]) * ww;
            }
        }
    }
    out[(size_t)d * 64 + lane] = __float2half(elu(acc + bias[lane]));
}

// ---------------- layer 2 ----------------

// h2 = act1h @ W2 via MFMA (fp16 in, fp32 acc, fp16 out) + fused layer-2 scores.
__global__ void k_h2m(const __half* __restrict__ act1h, const __half* __restrict__ W2t,
                      const float* __restrict__ a_src, const float* __restrict__ a_dst,
                      __half* __restrict__ h2h, float* __restrict__ ssrc,
                      float* __restrict__ sdst, int N) {
    __shared__ float sred[2][4][16];  // [src/dst][wave][node]
    int t = threadIdx.x;
    int wv = t >> 6, lane = t & 63;
    int lr = lane & 15, lg = lane >> 4;
    int n0 = blockIdx.x * 16;

    half8 a0 = {0, 0, 0, 0, 0, 0, 0, 0};
    half8 a1 = {0, 0, 0, 0, 0, 0, 0, 0};
    int nodeA = n0 + lr;
    if (nodeA < N) {
        a0 = *(const half8*)(act1h + (size_t)nodeA * 64 + lg * 8);
        a1 = *(const half8*)(act1h + (size_t)nodeA * 64 + 32 + lg * 8);
    }

    float ps[4] = {0.f, 0.f, 0.f, 0.f};
    float pd[4] = {0.f, 0.f, 0.f, 0.f};
#pragma unroll
    for (int c = 0; c < 4; ++c) {
        int col = wv * 64 + c * 16 + lr;
        half8 b0 = *(const half8*)(W2t + (size_t)col * 64 + lg * 8);
        half8 b1 = *(const half8*)(W2t + (size_t)col * 64 + 32 + lg * 8);
        floatx4 acc = {0.f, 0.f, 0.f, 0.f};
        acc = __builtin_amdgcn_mfma_f32_16x16x32_f16(a0, b0, acc, 0, 0, 0);
        acc = __builtin_amdgcn_mfma_f32_16x16x32_f16(a1, b1, acc, 0, 0, 0);
        float as = a_src[col], ad = a_dst[col];
#pragma unroll
        for (int r = 0; r < 4; ++r) {
            int node = n0 + lg * 4 + r;
            if (node < N) h2h[(size_t)node * 256 + col] = __float2half(acc[r]);
            ps[r] += acc[r] * as;
            pd[r] += acc[r] * ad;
        }
    }
#pragma unroll
    for (int r = 0; r < 4; ++r) {
#pragma unroll
        for (int off = 8; off >= 1; off >>= 1) {
            ps[r] += __shfl_xor(ps[r], off);
            pd[r] += __shfl_xor(pd[r], off);
        }
        if (lr == 0) {
            sred[0][wv][lg * 4 + r] = ps[r];
            sred[1][wv][lg * 4 + r] = pd[r];
        }
    }
    __syncthreads();
    if (t < 32) {
        int which = t >> 4, node = t & 15;
        int nn = n0 + node;
        if (nn < N) {
            float v = sred[which][0][node] + sred[which][1][node] +
                      sred[which][2][node] + sred[which][3][node];
            if (which == 0) ssrc[nn] = v; else sdst[nn] = v;
        }
    }
}

// gather GAT layer 2: wave per dst node; H=1, 256 channels (4 halves per lane); fused bias+elu
__global__ void k_gat2(const int* __restrict__ csr, const int* __restrict__ offs,
                       const int* __restrict__ deg,
                       const float* __restrict__ ssrc, const float* __restrict__ sdst,
                       const __half* __restrict__ h2h, const float* __restrict__ bias,
                       __half* __restrict__ act2h, int N) {
    int wave = threadIdx.x >> 6, lane = threadIdx.x & 63;
    int d = blockIdx.x * 4 + wave;
    if (d >= N) return;
    int start = offs[d], dg = deg[d];
    float sd = sdst[d];

    float m = -INFINITY;
    for (int j = lane; j < dg; j += 64)
        m = fmaxf(m, leaky(ssrc[csr[start + j]] + sd));
#pragma unroll
    for (int off = 32; off >= 1; off >>= 1) m = fmaxf(m, __shfl_xor(m, off));

    float den = 0.f;
    for (int j = lane; j < dg; j += 64)
        den += expf(leaky(ssrc[csr[start + j]] + sd) - m);
#pragma unroll
    for (int off = 32; off >= 1; off >>= 1) den += __shfl_xor(den, off);
    float inv = 1.f / (den + 1e-16f);

    float ax = 0.f, ay = 0.f, az = 0.f, aw = 0.f;
    for (int j0 = 0; j0 < dg; j0 += 64) {
        int j = j0 + lane;
        int se = 0;
        float w = 0.f;
        if (j < dg) {
            se = csr[start + j];
            w = expf(leaky(ssrc[se] + sd) - m) * inv;
        }
        int cnt = min(64, dg - j0);
        int cnt8 = (cnt + 7) & ~7;       // pad; padded lanes carry w=0, se=0
        for (int jj = 0; jj < cnt8; jj += 8) {
#pragma unroll
            for (int u = 0; u < 8; ++u) {
                int s2 = __shfl(se, jj + u);
                float ww = __shfl(w, jj + u);
                Half4 hv = *(const Half4*)(h2h + (size_t)s2 * 256 + lane * 4);
                float2 f0 = __half22float2(hv.a);
                float2 f1 = __half22float2(hv.b);
                ax += f0.x * ww;
                ay += f0.y * ww;
                az += f1.x * ww;
                aw += f1.y * ww;
            }
        }
    }
    float4 b = *(const float4*)(bias + lane * 4);
    Half4 o;
    o.a = __floats2half2_rn(elu(ax + b.x), elu(ay + b.y));
    o.b = __floats2half2_rn(elu(az + b.z), elu(aw + b.w));
    *(Half4*)(act2h + (size_t)d * 256 + lane * 4) = o;
}

// ---------------- pool + MLP (MFMA) ----------------

__global__ void k_pool(const __half* __restrict__ act2h, const int* __restrict__ batch, int N,
                       __half* __restrict__ pooledh) {
    int g = blockIdx.x;
    int t = threadIdx.x;
    int lo = 0, hi = N;
    while (lo < hi) { int mid = (lo + hi) >> 1; if (batch[mid] < g) lo = mid + 1; else hi = mid; }
    int start = lo;
    lo = start; hi = N;
    while (lo < hi) { int mid = (lo + hi) >> 1; if (batch[mid] < g + 1) lo = mid + 1; else hi = mid; }
    int end = lo;
    float m = -INFINITY;
    for (int n = start; n < end; ++n) m = fmaxf(m, __half2float(act2h[(size_t)n * 256 + t]));
    pooledh[g * 256 + t] = __float2half(m);  // max of fp16 values: exact
}

// C[M,N] = relu(A[M,K] @ W + b) with W supplied transposed Wt[N][K]; fp16 in/out, fp32 acc.
// block: 256 thr = 4 waves; tile 64 rows x 64 cols; grid (N/64, M/64). M,K,N multiples as launched.
__global__ void k_gemm(const __half* __restrict__ A, const __half* __restrict__ Wt,
                       const float* __restrict__ bias, __half* __restrict__ C,
                       int M, int N, int K, int relu) {
    int t = threadIdx.x;
    int wv = t >> 6, lane = t & 63;
    int lr = lane & 15, lg = lane >> 4;
    int bx = blockIdx.x, by = blockIdx.y;
    int arow = by * 64 + wv * 16 + lr;
    floatx4 acc[4] = {{0.f,0.f,0.f,0.f},{0.f,0.f,0.f,0.f},{0.f,0.f,0.f,0.f},{0.f,0.f,0.f,0.f}};
    for (int k0 = 0; k0 < K; k0 += 32) {
        half8 a = *(const half8*)(A + (size_t)arow * K + k0 + lg * 8);
#pragma unroll
        for (int c = 0; c < 4; ++c) {
            int col = bx * 64 + c * 16 + lr;
            half8 b = *(const half8*)(Wt + (size_t)col * K + k0 + lg * 8);
            acc[c] = __builtin_amdgcn_mfma_f32_16x16x32_f16(a, b, acc[c], 0, 0, 0);
        }
    }
#pragma unroll
    for (int c = 0; c < 4; ++c) {
        int col = bx * 64 + c * 16 + lr;
        float bv = bias[col];
#pragma unroll
        for (int r = 0; r < 4; ++r) {
            int row = by * 64 + wv * 16 + lg * 4 + r;
            float v = acc[c][r] + bv;
            if (relu) v = fmaxf(v, 0.f);
            C[(size_t)row * N + col] = __float2half(v);
        }
    }
}

// head: out[g,0:4] = z2[g,0:1024] @ Wl3 + bl3; block per graph
__global__ void k_mlp3(const __half* __restrict__ z2, const float* __restrict__ Wl3,
                       const float* __restrict__ bl3, float* __restrict__ out, int G) {
    __shared__ float sT[16];
    int g = blockIdx.x, t = threadIdx.x;
    int wave = t >> 6, lane = t & 63;
    float p[4] = {0.f, 0.f, 0.f, 0.f};
#pragma unroll
    for (int kk = 0; kk < 4; ++kk) {
        int k = t + kk * 256;
        float z = __half2float(z2[(size_t)g * 1024 + k]);
        float4 w = ((const float4*)Wl3)[k];
        p[0] += z * w.x; p[1] += z * w.y; p[2] += z * w.z; p[3] += z * w.w;
    }
#pragma unroll
    for (int c = 0; c < 4; ++c) {
#pragma unroll
        for (int off = 32; off >= 1; off >>= 1) p[c] += __shfl_xor(p[c], off);
        if (lane == 0) sT[wave * 4 + c] = p[c];
    }
    __syncthreads();
    if (t < 4) {
        float v = bl3[t] + sT[t] + sT[4 + t] + sT[8 + t] + sT[12 + t];
        out[(size_t)g * 4 + t] = v;
    }
}

extern "C" void kernel_launch(void* const* d_in, const int* in_sizes, int n_in,
                              void* d_out, int out_size, void* d_ws, size_t ws_size,
                              hipStream_t stream) {
    const float* x      = (const float*)d_in[0];
    const int*   ei     = (const int*)d_in[1];
    const int*   batch  = (const int*)d_in[2];
    const float* W1     = (const float*)d_in[3];
    const float* a_src1 = (const float*)d_in[4];
    const float* a_dst1 = (const float*)d_in[5];
    const float* b1     = (const float*)d_in[6];
    const float* W2     = (const float*)d_in[7];
    const float* a_src2 = (const float*)d_in[8];
    const float* a_dst2 = (const float*)d_in[9];
    const float* b2     = (const float*)d_in[10];
    const float* Wl1    = (const float*)d_in[11];
    const float* bl1    = (const float*)d_in[12];
    const float* Wl2    = (const float*)d_in[13];
    const float* bl2    = (const float*)d_in[14];
    const float* Wl3    = (const float*)d_in[15];
    const float* bl3    = (const float*)d_in[16];

    const int N = in_sizes[0] / 27;   // 50000
    const int E = in_sizes[1] / 2;    // 800000
    const int G = out_size / 4;       // 256
    const int EN = E + N;

    const int* srcA = ei;
    const int* dstA = ei + E;

    // ---- workspace layout (ints, fp32, then fp16; all chunks 16B-aligned) ----
    char* wp = (char*)d_ws;
    int* deg    = (int*)wp; wp += (size_t)N * 4;
    int* offs   = (int*)wp; wp += (size_t)N * 4;
    int* cursor = (int*)wp; wp += (size_t)N * 4;
    int* bsum   = (int*)wp; wp += (size_t)SCANB * 4;
    int* csr    = (int*)wp; wp += (size_t)EN * 4;

    float* ssrc1 = (float*)wp; wp += (size_t)N * 4 * 4;
    float* sdst1 = (float*)wp; wp += (size_t)N * 4 * 4;
    float* ssrc2 = (float*)wp; wp += (size_t)N * 4;
    float* sdst2 = (float*)wp; wp += (size_t)N * 4;

    __half* h1h   = (__half*)wp; wp += (size_t)N * 64 * 2;
    __half* act1h = (__half*)wp; wp += (size_t)N * 64 * 2;
    __half* h2h   = (__half*)wp; wp += (size_t)N * 256 * 2;
    __half* act2h = (__half*)wp; wp += (size_t)N * 256 * 2;
    __half* W2t   = (__half*)wp; wp += (size_t)64 * 256 * 2;
    __half* Wl1t  = (__half*)wp; wp += (size_t)512 * 256 * 2;
    __half* Wl2t  = (__half*)wp; wp += (size_t)1024 * 512 * 2;
    __half* pooledh = (__half*)wp; wp += (size_t)G * 256 * 2;
    __half* z1h   = (__half*)wp; wp += (size_t)G * 512 * 2;
    __half* z2h   = (__half*)wp; wp += (size_t)G * 1024 * 2;

    const int nb = (N + SCANB - 1) / SCANB;  // 196 <= 256

    // ---- weight prep (transpose to [n][k] fp16) ----
    k_t<<<(64 * 256 + 255) / 256, 256, 0, stream>>>(W2, W2t, 64, 256);
    k_t<<<(256 * 512 + 255) / 256, 256, 0, stream>>>(Wl1, Wl1t, 256, 512);
    k_t<<<(512 * 1024 + 255) / 256, 256, 0, stream>>>(Wl2, Wl2t, 512, 1024);

    // ---- CSR build (shared by both layers) ----
    hipMemsetAsync(deg, 0, (size_t)N * 4, stream);
    k_hist<<<(EN + 255) / 256, 256, 0, stream>>>(srcA, dstA, E, N, deg);
    k_scan1<<<nb, SCANB, 0, stream>>>(deg, offs, bsum, N);
    k_scan2<<<1, SCANB, 0, stream>>>(bsum, nb);
    k_scan3<<<nb, SCANB, 0, stream>>>(offs, bsum, N);
    hipMemcpyAsync(cursor, offs, (size_t)N * 4, hipMemcpyDeviceToDevice, stream);
    k_scatter<<<(EN + 255) / 256, 256, 0, stream>>>(srcA, dstA, E, N, cursor, csr);

    // ---- layer 1 ----
    k_h1<<<(N + 3) / 4, 256, 0, stream>>>(x, W1, a_src1, a_dst1, h1h, ssrc1, sdst1, N);
    k_gat1<<<(N + 3) / 4, 256, 0, stream>>>(csr, offs, deg, ssrc1, sdst1, h1h, b1, act1h, N);

    // ---- layer 2 ----
    k_h2m<<<(N + 15) / 16, 256, 0, stream>>>(act1h, W2t, a_src2, a_dst2, h2h, ssrc2, sdst2, N);
    k_gat2<<<(N + 3) / 4, 256, 0, stream>>>(csr, offs, deg, ssrc2, sdst2, h2h, b2, act2h, N);

    // ---- pool + MLP ----
    k_pool<<<G, 256, 0, stream>>>(act2h, batch, N, pooledh);
    k_gemm<<<dim3(512 / 64, 256 / 64), 256, 0, stream>>>(pooledh, Wl1t, bl1, z1h, 256, 512, 256, 1);
    k_gemm<<<dim3(1024 / 64, 256 / 64), 256, 0, stream>>>(z1h, Wl2t, bl2, z2h, 256, 1024, 512, 1);
    k_mlp3<<<G, 256, 0, stream>>>(z2h, Wl3, bl3, (float*)d_out, G);
}

// Round 8
// 315.692 us; speedup vs baseline: 5.7593x; 1.0686x over previous
//
#include <hip/hip_runtime.h>
#include <hip/hip_fp16.h>
#include <math.h>

#define NEG_SLOPE 0.2f
#define SCANB 256

__device__ __forceinline__ float leaky(float x) { return x >= 0.f ? x : NEG_SLOPE * x; }
__device__ __forceinline__ float elu(float x) { return x > 0.f ? x : expm1f(x); }

struct Half4 { __half2 a, b; };

typedef _Float16 half8 __attribute__((ext_vector_type(8)));
typedef float floatx4 __attribute__((ext_vector_type(4)));

// ---------------- CSR build ----------------

__global__ void k_hist(const int* __restrict__ src, const int* __restrict__ dst, int E, int N,
                       int* __restrict__ deg) {
    int e = blockIdx.x * blockDim.x + threadIdx.x;
    if (e >= E + N) return;
    int d = (e < E) ? dst[e] : e - E;
    atomicAdd(&deg[d], 1);
}

__global__ void k_scan1(const int* __restrict__ in, int* __restrict__ out,
                        int* __restrict__ bsum, int N) {
    __shared__ int sm[SCANB];
    int i = blockIdx.x * SCANB + threadIdx.x;
    int v = (i < N) ? in[i] : 0;
    sm[threadIdx.x] = v;
    __syncthreads();
    for (int off = 1; off < SCANB; off <<= 1) {
        int t = (threadIdx.x >= off) ? sm[threadIdx.x - off] : 0;
        __syncthreads();
        sm[threadIdx.x] += t;
        __syncthreads();
    }
    if (i < N) out[i] = sm[threadIdx.x] - v;  // exclusive
    if (threadIdx.x == SCANB - 1) bsum[blockIdx.x] = sm[SCANB - 1];
}

__global__ void k_scan2(int* __restrict__ bsum, int nb) {
    __shared__ int sm[SCANB];
    int v = (threadIdx.x < nb) ? bsum[threadIdx.x] : 0;
    sm[threadIdx.x] = v;
    __syncthreads();
    for (int off = 1; off < SCANB; off <<= 1) {
        int t = (threadIdx.x >= off) ? sm[threadIdx.x - off] : 0;
        __syncthreads();
        sm[threadIdx.x] += t;
        __syncthreads();
    }
    if (threadIdx.x < nb) bsum[threadIdx.x] = sm[threadIdx.x] - v;
}

__global__ void k_scan3(int* __restrict__ out, int* __restrict__ cursor,
                        const int* __restrict__ bsum, int N) {
    int i = blockIdx.x * SCANB + threadIdx.x;
    if (i < N) {
        int v = out[i] + bsum[blockIdx.x];
        out[i] = v;
        cursor[i] = v;
    }
}

__global__ void k_scatter(const int* __restrict__ src, const int* __restrict__ dst, int E, int N,
                          int* __restrict__ cursor, int* __restrict__ csr) {
    int e = blockIdx.x * blockDim.x + threadIdx.x;
    if (e >= E + N) return;
    int s, d;
    if (e < E) { s = src[e]; d = dst[e]; } else { s = d = e - E; }
    int pos = atomicAdd(&cursor[d], 1);
    csr[pos] = s;
}

// ---------------- fused weight prep ----------------
// ranges: [0,16384) W2->W2t ; [16384,147456) Wl1->Wl1t ; [147456,671744) Wl2->Wl2t ;
// [671744,671872) ws2/wd2 = W2 @ a_src2 / a_dst2
__global__ void k_prep(const float* __restrict__ W2, __half* __restrict__ W2t,
                       const float* __restrict__ Wl1, __half* __restrict__ Wl1t,
                       const float* __restrict__ Wl2, __half* __restrict__ Wl2t,
                       const float* __restrict__ a_src2, const float* __restrict__ a_dst2,
                       float* __restrict__ ws2, float* __restrict__ wd2) {
    int i = blockIdx.x * blockDim.x + threadIdx.x;
    if (i < 16384) {
        int k = i >> 8, n = i & 255;
        W2t[(size_t)n * 64 + k] = __float2half(W2[i]);
    } else if (i < 16384 + 131072) {
        int j = i - 16384;
        int k = j >> 9, n = j & 511;
        Wl1t[(size_t)n * 256 + k] = __float2half(Wl1[j]);
    } else if (i < 16384 + 131072 + 524288) {
        int j = i - 16384 - 131072;
        int k = j >> 10, n = j & 1023;
        Wl2t[(size_t)n * 512 + k] = __float2half(Wl2[j]);
    } else if (i < 16384 + 131072 + 524288 + 128) {
        int j = i - 16384 - 131072 - 524288;
        int k = j & 63;
        const float* av = (j < 64) ? a_src2 : a_dst2;
        float acc = 0.f;
        for (int c = 0; c < 256; ++c) acc += W2[k * 256 + c] * av[c];
        if (j < 64) ws2[k] = acc; else wd2[k] = acc;
    }
}

// ---------------- layer 1 ----------------

// h1 = x @ W1  [N,27]@[27,64] (fp16 out), plus per-head scores s_src/s_dst [N,4] (fp32)
__global__ void k_h1(const float* __restrict__ x, const float* __restrict__ W1,
                     const float* __restrict__ a_src, const float* __restrict__ a_dst,
                     __half* __restrict__ h1h, float* __restrict__ ssrc, float* __restrict__ sdst,
                     int N) {
    __shared__ float sW[27 * 64];
    for (int i = threadIdx.x; i < 27 * 64; i += blockDim.x) sW[i] = W1[i];
    __syncthreads();
    int wave = threadIdx.x >> 6;
    int lane = threadIdx.x & 63;
    int n = blockIdx.x * 4 + wave;
    if (n >= N) return;
    const float* xr = x + (size_t)n * 27;
    float acc = 0.f;
#pragma unroll
    for (int k = 0; k < 27; ++k) acc += xr[k] * sW[k * 64 + lane];
    h1h[(size_t)n * 64 + lane] = __float2half(acc);
    int hd = lane >> 4, c = lane & 15;
    float vs = acc * a_src[hd * 16 + c];
    float vd = acc * a_dst[hd * 16 + c];
#pragma unroll
    for (int off = 8; off >= 1; off >>= 1) {
        vs += __shfl_xor(vs, off);
        vd += __shfl_xor(vd, off);
    }
    if (c == 0) {
        ssrc[n * 4 + hd] = vs;
        sdst[n * 4 + hd] = vd;
    }
}

// gather GAT layer 1 + fused layer-2 score dots (ssrc2/sdst2 via ws2/wd2)
__global__ void k_gat1(const int* __restrict__ csr, const int* __restrict__ offs,
                       const int* __restrict__ deg,
                       const float* __restrict__ ssrc, const float* __restrict__ sdst,
                       const __half* __restrict__ h1h, const float* __restrict__ bias,
                       const float* __restrict__ ws2, const float* __restrict__ wd2,
                       __half* __restrict__ out, float* __restrict__ ssrc2,
                       float* __restrict__ sdst2, int N) {
    int wave = threadIdx.x >> 6, lane = threadIdx.x & 63;
    int d = blockIdx.x * 4 + wave;
    if (d >= N) return;
    int start = offs[d], dg = deg[d];
    float4 sd = *(const float4*)(sdst + (size_t)d * 4);

    float m0 = -INFINITY, m1 = -INFINITY, m2 = -INFINITY, m3 = -INFINITY;
    for (int j = lane; j < dg; j += 64) {
        int s = csr[start + j];
        float4 a = *(const float4*)(ssrc + (size_t)s * 4);
        m0 = fmaxf(m0, leaky(a.x + sd.x));
        m1 = fmaxf(m1, leaky(a.y + sd.y));
        m2 = fmaxf(m2, leaky(a.z + sd.z));
        m3 = fmaxf(m3, leaky(a.w + sd.w));
    }
#pragma unroll
    for (int off = 32; off >= 1; off >>= 1) {
        m0 = fmaxf(m0, __shfl_xor(m0, off));
        m1 = fmaxf(m1, __shfl_xor(m1, off));
        m2 = fmaxf(m2, __shfl_xor(m2, off));
        m3 = fmaxf(m3, __shfl_xor(m3, off));
    }
    float e0 = 0.f, e1 = 0.f, e2 = 0.f, e3 = 0.f;
    for (int j = lane; j < dg; j += 64) {
        int s = csr[start + j];
        float4 a = *(const float4*)(ssrc + (size_t)s * 4);
        e0 += expf(leaky(a.x + sd.x) - m0);
        e1 += expf(leaky(a.y + sd.y) - m1);
        e2 += expf(leaky(a.z + sd.z) - m2);
        e3 += expf(leaky(a.w + sd.w) - m3);
    }
#pragma unroll
    for (int off = 32; off >= 1; off >>= 1) {
        e0 += __shfl_xor(e0, off);
        e1 += __shfl_xor(e1, off);
        e2 += __shfl_xor(e2, off);
        e3 += __shfl_xor(e3, off);
    }
    float i0 = 1.f / (e0 + 1e-16f), i1 = 1.f / (e1 + 1e-16f);
    float i2 = 1.f / (e2 + 1e-16f), i3 = 1.f / (e3 + 1e-16f);

    int hd = lane >> 4;
    int eidx = lane & 15;
    int base = lane & 48;  // 16*hd
    float mh  = hd == 0 ? m0 : hd == 1 ? m1 : hd == 2 ? m2 : m3;
    float ih  = hd == 0 ? i0 : hd == 1 ? i1 : hd == 2 ? i2 : i3;
    float sdh = hd == 0 ? sd.x : hd == 1 ? sd.y : hd == 2 ? sd.z : sd.w;

    float acc = 0.f;
    for (int j0 = 0; j0 < dg; j0 += 16) {
        int j = j0 + eidx;
        int se = 0;
        float w = 0.f;
        if (j < dg) {
            se = csr[start + j];
            float a = ssrc[(size_t)se * 4 + hd];
            w = expf(leaky(a + sdh) - mh) * ih;
        }
        int cnt = min(16, dg - j0);
        int cnt8 = (cnt + 7) & ~7;       // pad; padded lanes carry w=0, se=0
        for (int jj = 0; jj < cnt8; jj += 8) {
#pragma unroll
            for (int u = 0; u < 8; ++u) {
                int s2 = __shfl(se, jj + u);            // lanes 0-15 hold edge ids
                float ww = __shfl(w, base + jj + u);    // head-specific weight
                acc += __half2float(h1h[(size_t)s2 * 64 + lane]) * ww;
            }
        }
    }
    float av = elu(acc + bias[lane]);
    out[(size_t)d * 64 + lane] = __float2half(av);
    // fused layer-2 scores: s2[d] = act1[d,:] . (W2 @ a2)
    float vs = av * ws2[lane];
    float vd = av * wd2[lane];
#pragma unroll
    for (int off = 32; off >= 1; off >>= 1) {
        vs += __shfl_xor(vs, off);
        vd += __shfl_xor(vd, off);
    }
    if (lane == 0) { ssrc2[d] = vs; sdst2[d] = vd; }
}

// ---------------- layer 2 ----------------

// gather-aggregate act1 (64 fp16 ch) with layer-2 softmax weights -> aggh [N,64]
__global__ void k_gat2a(const int* __restrict__ csr, const int* __restrict__ offs,
                        const int* __restrict__ deg,
                        const float* __restrict__ ssrc, const float* __restrict__ sdst,
                        const __half* __restrict__ act1h, __half* __restrict__ aggh, int N) {
    int wave = threadIdx.x >> 6, lane = threadIdx.x & 63;
    int d = blockIdx.x * 4 + wave;
    if (d >= N) return;
    int start = offs[d], dg = deg[d];
    float sd = sdst[d];

    float m = -INFINITY;
    for (int j = lane; j < dg; j += 64)
        m = fmaxf(m, leaky(ssrc[csr[start + j]] + sd));
#pragma unroll
    for (int off = 32; off >= 1; off >>= 1) m = fmaxf(m, __shfl_xor(m, off));

    float den = 0.f;
    for (int j = lane; j < dg; j += 64)
        den += expf(leaky(ssrc[csr[start + j]] + sd) - m);
#pragma unroll
    for (int off = 32; off >= 1; off >>= 1) den += __shfl_xor(den, off);
    float inv = 1.f / (den + 1e-16f);

    float acc = 0.f;
    for (int j0 = 0; j0 < dg; j0 += 64) {
        int j = j0 + lane;
        int se = 0;
        float w = 0.f;
        if (j < dg) {
            se = csr[start + j];
            w = expf(leaky(ssrc[se] + sd) - m) * inv;
        }
        int cnt = min(64, dg - j0);
        int cnt8 = (cnt + 7) & ~7;       // pad; padded lanes carry w=0, se=0
        for (int jj = 0; jj < cnt8; jj += 8) {
#pragma unroll
            for (int u = 0; u < 8; ++u) {
                int s2 = __shfl(se, jj + u);
                float ww = __shfl(w, jj + u);
                acc += __half2float(act1h[(size_t)s2 * 64 + lane]) * ww;
            }
        }
    }
    aggh[(size_t)d * 64 + lane] = __float2half(acc);
}

// act2 = elu(aggh @ W2 + b2); MFMA 16 nodes/block, 4 waves over 256 cols
__global__ void k_h2b(const __half* __restrict__ aggh, const __half* __restrict__ W2t,
                      const float* __restrict__ b2, __half* __restrict__ act2h, int N) {
    int t = threadIdx.x;
    int wv = t >> 6, lane = t & 63;
    int lr = lane & 15, lg = lane >> 4;
    int n0 = blockIdx.x * 16;

    half8 a0 = {0, 0, 0, 0, 0, 0, 0, 0};
    half8 a1 = {0, 0, 0, 0, 0, 0, 0, 0};
    int nodeA = n0 + lr;
    if (nodeA < N) {
        a0 = *(const half8*)(aggh + (size_t)nodeA * 64 + lg * 8);
        a1 = *(const half8*)(aggh + (size_t)nodeA * 64 + 32 + lg * 8);
    }
#pragma unroll
    for (int c = 0; c < 4; ++c) {
        int col = wv * 64 + c * 16 + lr;
        half8 b0 = *(const half8*)(W2t + (size_t)col * 64 + lg * 8);
        half8 b1 = *(const half8*)(W2t + (size_t)col * 64 + 32 + lg * 8);
        floatx4 acc = {0.f, 0.f, 0.f, 0.f};
        acc = __builtin_amdgcn_mfma_f32_16x16x32_f16(a0, b0, acc, 0, 0, 0);
        acc = __builtin_amdgcn_mfma_f32_16x16x32_f16(a1, b1, acc, 0, 0, 0);
        float bv = b2[col];
#pragma unroll
        for (int r = 0; r < 4; ++r) {
            int node = n0 + lg * 4 + r;
            if (node < N) act2h[(size_t)node * 256 + col] = __float2half(elu(acc[r] + bv));
        }
    }
}

// ---------------- pool + MLP (MFMA) ----------------

__global__ void k_pool(const __half* __restrict__ act2h, const int* __restrict__ batch, int N,
                       __half* __restrict__ pooledh) {
    int g = blockIdx.x;
    int t = threadIdx.x;
    int lo = 0, hi = N;
    while (lo < hi) { int mid = (lo + hi) >> 1; if (batch[mid] < g) lo = mid + 1; else hi = mid; }
    int start = lo;
    lo = start; hi = N;
    while (lo < hi) { int mid = (lo + hi) >> 1; if (batch[mid] < g + 1) lo = mid + 1; else hi = mid; }
    int end = lo;
    float m = -INFINITY;
    for (int n = start; n < end; ++n) m = fmaxf(m, __half2float(act2h[(size_t)n * 256 + t]));
    pooledh[g * 256 + t] = __float2half(m);  // max of fp16 values: exact
}

// C[M,N] = relu(A[M,K] @ W + b) with W transposed Wt[N][K]; fp16 in/out, fp32 acc.
__global__ void k_gemm(const __half* __restrict__ A, const __half* __restrict__ Wt,
                       const float* __restrict__ bias, __half* __restrict__ C,
                       int M, int N, int K, int relu) {
    int t = threadIdx.x;
    int wv = t >> 6, lane = t & 63;
    int lr = lane & 15, lg = lane >> 4;
    int bx = blockIdx.x, by = blockIdx.y;
    int arow = by * 64 + wv * 16 + lr;
    floatx4 acc[4] = {{0.f,0.f,0.f,0.f},{0.f,0.f,0.f,0.f},{0.f,0.f,0.f,0.f},{0.f,0.f,0.f,0.f}};
    for (int k0 = 0; k0 < K; k0 += 32) {
        half8 a = *(const half8*)(A + (size_t)arow * K + k0 + lg * 8);
#pragma unroll
        for (int c = 0; c < 4; ++c) {
            int col = bx * 64 + c * 16 + lr;
            half8 b = *(const half8*)(Wt + (size_t)col * K + k0 + lg * 8);
            acc[c] = __builtin_amdgcn_mfma_f32_16x16x32_f16(a, b, acc[c], 0, 0, 0);
        }
    }
#pragma unroll
    for (int c = 0; c < 4; ++c) {
        int col = bx * 64 + c * 16 + lr;
        float bv = bias[col];
#pragma unroll
        for (int r = 0; r < 4; ++r) {
            int row = by * 64 + wv * 16 + lg * 4 + r;
            float v = acc[c][r] + bv;
            if (relu) v = fmaxf(v, 0.f);
            C[(size_t)row * N + col] = __float2half(v);
        }
    }
}

// head: out[g,0:4] = z2[g,0:1024] @ Wl3 + bl3; block per graph
__global__ void k_mlp3(const __half* __restrict__ z2, const float* __restrict__ Wl3,
                       const float* __restrict__ bl3, float* __restrict__ out, int G) {
    __shared__ float sT[16];
    int g = blockIdx.x, t = threadIdx.x;
    int wave = t >> 6, lane = t & 63;
    float p[4] = {0.f, 0.f, 0.f, 0.f};
#pragma unroll
    for (int kk = 0; kk < 4; ++kk) {
        int k = t + kk * 256;
        float z = __half2float(z2[(size_t)g * 1024 + k]);
        float4 w = ((const float4*)Wl3)[k];
        p[0] += z * w.x; p[1] += z * w.y; p[2] += z * w.z; p[3] += z * w.w;
    }
#pragma unroll
    for (int c = 0; c < 4; ++c) {
#pragma unroll
        for (int off = 32; off >= 1; off >>= 1) p[c] += __shfl_xor(p[c], off);
        if (lane == 0) sT[wave * 4 + c] = p[c];
    }
    __syncthreads();
    if (t < 4) {
        float v = bl3[t] + sT[t] + sT[4 + t] + sT[8 + t] + sT[12 + t];
        out[(size_t)g * 4 + t] = v;
    }
}

extern "C" void kernel_launch(void* const* d_in, const int* in_sizes, int n_in,
                              void* d_out, int out_size, void* d_ws, size_t ws_size,
                              hipStream_t stream) {
    const float* x      = (const float*)d_in[0];
    const int*   ei     = (const int*)d_in[1];
    const int*   batch  = (const int*)d_in[2];
    const float* W1     = (const float*)d_in[3];
    const float* a_src1 = (const float*)d_in[4];
    const float* a_dst1 = (const float*)d_in[5];
    const float* b1     = (const float*)d_in[6];
    const float* W2     = (const float*)d_in[7];
    const float* a_src2 = (const float*)d_in[8];
    const float* a_dst2 = (const float*)d_in[9];
    const float* b2     = (const float*)d_in[10];
    const float* Wl1    = (const float*)d_in[11];
    const float* bl1    = (const float*)d_in[12];
    const float* Wl2    = (const float*)d_in[13];
    const float* bl2    = (const float*)d_in[14];
    const float* Wl3    = (const float*)d_in[15];
    const float* bl3    = (const float*)d_in[16];

    const int N = in_sizes[0] / 27;   // 50000
    const int E = in_sizes[1] / 2;    // 800000
    const int G = out_size / 4;       // 256
    const int EN = E + N;

    const int* srcA = ei;
    const int* dstA = ei + E;

    // ---- workspace layout ----
    char* wp = (char*)d_ws;
    int* deg    = (int*)wp; wp += (size_t)N * 4;
    int* offs   = (int*)wp; wp += (size_t)N * 4;
    int* cursor = (int*)wp; wp += (size_t)N * 4;
    int* bsum   = (int*)wp; wp += (size_t)SCANB * 4;
    int* csr    = (int*)wp; wp += (size_t)EN * 4;

    float* ssrc1 = (float*)wp; wp += (size_t)N * 4 * 4;
    float* sdst1 = (float*)wp; wp += (size_t)N * 4 * 4;
    float* ssrc2 = (float*)wp; wp += (size_t)N * 4;
    float* sdst2 = (float*)wp; wp += (size_t)N * 4;
    float* ws2   = (float*)wp; wp += 64 * 4;
    float* wd2   = (float*)wp; wp += 64 * 4;

    __half* h1h   = (__half*)wp; wp += (size_t)N * 64 * 2;
    __half* act1h = (__half*)wp; wp += (size_t)N * 64 * 2;
    __half* aggh  = (__half*)wp; wp += (size_t)N * 64 * 2;
    __half* act2h = (__half*)wp; wp += (size_t)N * 256 * 2;
    __half* W2t   = (__half*)wp; wp += (size_t)64 * 256 * 2;
    __half* Wl1t  = (__half*)wp; wp += (size_t)512 * 256 * 2;
    __half* Wl2t  = (__half*)wp; wp += (size_t)1024 * 512 * 2;
    __half* pooledh = (__half*)wp; wp += (size_t)G * 256 * 2;
    __half* z1h   = (__half*)wp; wp += (size_t)G * 512 * 2;
    __half* z2h   = (__half*)wp; wp += (size_t)G * 1024 * 2;

    const int nb = (N + SCANB - 1) / SCANB;  // 196 <= 256

    // ---- fused weight prep ----
    {
        int tot = 16384 + 131072 + 524288 + 128;
        k_prep<<<(tot + 255) / 256, 256, 0, stream>>>(W2, W2t, Wl1, Wl1t, Wl2, Wl2t,
                                                      a_src2, a_dst2, ws2, wd2);
    }

    // ---- CSR build (shared by both layers) ----
    hipMemsetAsync(deg, 0, (size_t)N * 4, stream);
    k_hist<<<(EN + 255) / 256, 256, 0, stream>>>(srcA, dstA, E, N, deg);
    k_scan1<<<nb, SCANB, 0, stream>>>(deg, offs, bsum, N);
    k_scan2<<<1, SCANB, 0, stream>>>(bsum, nb);
    k_scan3<<<nb, SCANB, 0, stream>>>(offs, cursor, bsum, N);
    k_scatter<<<(EN + 255) / 256, 256, 0, stream>>>(srcA, dstA, E, N, cursor, csr);

    // ---- layer 1 (+ fused layer-2 score dots) ----
    k_h1<<<(N + 3) / 4, 256, 0, stream>>>(x, W1, a_src1, a_dst1, h1h, ssrc1, sdst1, N);
    k_gat1<<<(N + 3) / 4, 256, 0, stream>>>(csr, offs, deg, ssrc1, sdst1, h1h, b1,
                                            ws2, wd2, act1h, ssrc2, sdst2, N);

    // ---- layer 2: aggregate act1 then GEMM by W2 ----
    k_gat2a<<<(N + 3) / 4, 256, 0, stream>>>(csr, offs, deg, ssrc2, sdst2, act1h, aggh, N);
    k_h2b<<<(N + 15) / 16, 256, 0, stream>>>(aggh, W2t, b2, act2h, N);

    // ---- pool + MLP ----
    k_pool<<<G, 256, 0, stream>>>(act2h, batch, N, pooledh);
    k_gemm<<<dim3(512 / 64, 256 / 64), 256, 0, stream>>>(pooledh, Wl1t, bl1, z1h, 256, 512, 256, 1);
    k_gemm<<<dim3(1024 / 64, 256 / 64), 256, 0, stream>>>(z1h, Wl2t, bl2, z2h, 256, 1024, 512, 1);
    k_mlp3<<<G, 256, 0, stream>>>(z2h, Wl3, bl3, (float*)d_out, G);
}